// Round 2
// baseline (5705.794 us; speedup 1.0000x reference)
//
#include <hip/hip_runtime.h>

// ---------------------------------------------------------------------------
// Problem constants
// ---------------------------------------------------------------------------
#define N_PFAS 20000
#define N_GW   100000
#define N_SW   30000
#define E_PG   1600000
#define E_GP   640000
#define E_PS   480000
#define E_SP   320000
// D = OUT = 128 throughout.

enum { MODE_T = 0, MODE_SCALAR = 1, MODE_PF_BASE = 2 };

// ---------------------------------------------------------------------------
// Tiled GEMM: out-rows = X[n,128] @ W[128,128] with fused epilogues.
// Block: 256 threads, 128 rows. LDS: 32 KB (two 16 KB k-chunk tiles).
// Thread (tx=tid&31, ty=tid>>5) computes 16 rows x 4 cols (float4 acc[16]).
// MODE_T:       out[r,:] = X@Wa                         (plain transform)
// MODE_SCALAR:  h = relu(X@Wa + b1 + agg/cnt); out[r] = h . wout + bout
// MODE_PF_BASE: out[r,:] = X@(Wa+Wb) + b1 + b2          (no relu)
// ---------------------------------------------------------------------------
template<int MODE>
__global__ __launch_bounds__(256) void gemm_epi(
    int n, const float* __restrict__ X, const float* __restrict__ Wa,
    const float* __restrict__ Wb, const float* __restrict__ b1,
    const float* __restrict__ b2, const float* __restrict__ agg,
    const float* __restrict__ cnt, const float* __restrict__ wout,
    const float* __restrict__ bout, float* __restrict__ out)
{
    __shared__ float sW[32 * 128];   // [k][col], k-chunk of W
    __shared__ float sX[32 * 128];   // [k][row], k-chunk of X tile (transposed)
    float4* sW4 = (float4*)sW;

    const int tid = threadIdx.x;
    const int tx = tid & 31;   // col group: cols [4tx, 4tx+4)
    const int ty = tid >> 5;   // row group: rows [16ty, 16ty+16)
    const int row0 = blockIdx.x * 128;

    float4 acc[16];
#pragma unroll
    for (int i = 0; i < 16; ++i) acc[i] = make_float4(0.f, 0.f, 0.f, 0.f);

    const float4* X4 = (const float4*)X;
    const float4* Wa4 = (const float4*)Wa;
    const float4* Wb4 = (const float4*)Wb;

    for (int kc = 0; kc < 4; ++kc) {
        __syncthreads();
        // stage W chunk (rows kc*32..+32, all 128 cols) = 1024 float4
        for (int i = tid; i < 1024; i += 256) {
            float4 w = Wa4[kc * 1024 + i];
            if (MODE == MODE_PF_BASE) {
                float4 wb = Wb4[kc * 1024 + i];
                w.x += wb.x; w.y += wb.y; w.z += wb.z; w.w += wb.w;
            }
            sW4[i] = w;
        }
        // stage X tile transposed: 128 rows x 32 k
        for (int j = tid; j < 1024; j += 256) {
            int rr = j >> 3, k4 = j & 7;
            int r = row0 + rr;
            float4 xv = make_float4(0.f, 0.f, 0.f, 0.f);
            if (r < n) xv = X4[(size_t)r * 32 + kc * 8 + k4];
            int kk = k4 * 4;
            sX[(kk + 0) * 128 + rr] = xv.x;
            sX[(kk + 1) * 128 + rr] = xv.y;
            sX[(kk + 2) * 128 + rr] = xv.z;
            sX[(kk + 3) * 128 + rr] = xv.w;
        }
        __syncthreads();
#pragma unroll 4
        for (int k = 0; k < 32; ++k) {
            float4 w4 = sW4[k * 32 + tx];
            const float4* xr4 = (const float4*)&sX[k * 128 + ty * 16];
#pragma unroll
            for (int q = 0; q < 4; ++q) {
                float4 x4 = xr4[q];
                acc[q * 4 + 0].x += x4.x * w4.x; acc[q * 4 + 0].y += x4.x * w4.y;
                acc[q * 4 + 0].z += x4.x * w4.z; acc[q * 4 + 0].w += x4.x * w4.w;
                acc[q * 4 + 1].x += x4.y * w4.x; acc[q * 4 + 1].y += x4.y * w4.y;
                acc[q * 4 + 1].z += x4.y * w4.z; acc[q * 4 + 1].w += x4.y * w4.w;
                acc[q * 4 + 2].x += x4.z * w4.x; acc[q * 4 + 2].y += x4.z * w4.y;
                acc[q * 4 + 2].z += x4.z * w4.z; acc[q * 4 + 2].w += x4.z * w4.w;
                acc[q * 4 + 3].x += x4.w * w4.x; acc[q * 4 + 3].y += x4.w * w4.y;
                acc[q * 4 + 3].z += x4.w * w4.z; acc[q * 4 + 3].w += x4.w * w4.w;
            }
        }
    }

    const int rbase = row0 + ty * 16;
    if (MODE == MODE_T) {
#pragma unroll
        for (int rr = 0; rr < 16; ++rr) {
            int r = rbase + rr;
            if (r < n) ((float4*)out)[(size_t)r * 32 + tx] = acc[rr];
        }
    } else if (MODE == MODE_PF_BASE) {
        float4 bv1 = ((const float4*)b1)[tx];
        float4 bv2 = ((const float4*)b2)[tx];
#pragma unroll
        for (int rr = 0; rr < 16; ++rr) {
            int r = rbase + rr;
            if (r < n) {
                float4 o = acc[rr];
                o.x += bv1.x + bv2.x; o.y += bv1.y + bv2.y;
                o.z += bv1.z + bv2.z; o.w += bv1.w + bv2.w;
                ((float4*)out)[(size_t)r * 32 + tx] = o;
            }
        }
    } else {  // MODE_SCALAR
        float4 bv = ((const float4*)b1)[tx];
        float4 wo = ((const float4*)wout)[tx];
        float bo = bout[0];
#pragma unroll
        for (int rr = 0; rr < 16; ++rr) {
            int r = rbase + rr;
            float inv = 0.f;
            float4 a4 = make_float4(0.f, 0.f, 0.f, 0.f);
            if (r < n) {
                inv = 1.0f / fmaxf(cnt[r], 1.0f);
                a4 = ((const float4*)agg)[(size_t)r * 32 + tx];
            }
            float h0 = fmaxf(acc[rr].x + bv.x + a4.x * inv, 0.f);
            float h1 = fmaxf(acc[rr].y + bv.y + a4.y * inv, 0.f);
            float h2 = fmaxf(acc[rr].z + bv.z + a4.z * inv, 0.f);
            float h3 = fmaxf(acc[rr].w + bv.w + a4.w * inv, 0.f);
            float p = h0 * wo.x + h1 * wo.y + h2 * wo.z + h3 * wo.w;
            p += __shfl_xor(p, 1, 32);
            p += __shfl_xor(p, 2, 32);
            p += __shfl_xor(p, 4, 32);
            p += __shfl_xor(p, 8, 32);
            p += __shfl_xor(p, 16, 32);
            if (tx == 0 && r < n) out[r] = p + bo;
        }
    }
}

// ---------------------------------------------------------------------------
// Edge scatter: 32 threads/edge; thread handles 4 consecutive floats.
// agg[dst] += src_feat[src]; cnt[dst] += 1.
// ---------------------------------------------------------------------------
__global__ __launch_bounds__(256) void scatter_kernel(
    const float4* __restrict__ xsrc, const int* __restrict__ src,
    const int* __restrict__ dst, int E,
    float* __restrict__ agg, float* __restrict__ cnt)
{
    int id = blockIdx.x * 256 + threadIdx.x;
    int e = id >> 5;
    if (e >= E) return;
    int part = id & 31;
    int s = src[e];
    int d = dst[e];
    float4 v = xsrc[(size_t)s * 32 + part];
    float* a = agg + (size_t)d * 128 + part * 4;
    atomicAdd(a + 0, v.x);
    atomicAdd(a + 1, v.y);
    atomicAdd(a + 2, v.z);
    atomicAdd(a + 3, v.w);
    if (part == 0) atomicAdd(cnt + d, 1.0f);
}

// ---------------------------------------------------------------------------
// h[r,:] += agg[r,:]/max(cnt[r],1); optional relu.
// ---------------------------------------------------------------------------
__global__ __launch_bounds__(256) void addmean_kernel(
    int n, const float* __restrict__ agg, const float* __restrict__ cnt,
    float* __restrict__ h, int do_relu)
{
    int id = blockIdx.x * 256 + threadIdx.x;
    if (id >= n * 32) return;
    int r = id >> 5;
    float inv = 1.0f / fmaxf(cnt[r], 1.0f);
    float4 a = ((const float4*)agg)[id];
    float4 v = ((float4*)h)[id];
    v.x += a.x * inv; v.y += a.y * inv; v.z += a.z * inv; v.w += a.w * inv;
    if (do_relu) {
        v.x = fmaxf(v.x, 0.f); v.y = fmaxf(v.y, 0.f);
        v.z = fmaxf(v.z, 0.f); v.w = fmaxf(v.w, 0.f);
    }
    ((float4*)h)[id] = v;
}

// ---------------------------------------------------------------------------
// Launch
// ---------------------------------------------------------------------------
extern "C" void kernel_launch(void* const* d_in, const int* in_sizes, int n_in,
                              void* d_out, int out_size, void* d_ws, size_t ws_size,
                              hipStream_t stream)
{
    const float* x_pfas = (const float*)d_in[0];
    const float* x_gw   = (const float*)d_in[1];
    const float* x_sw   = (const float*)d_in[2];
    const int* ei_pg_src = (const int*)d_in[3];
    const int* ei_pg_dst = (const int*)d_in[4];
    const int* ei_gp_src = (const int*)d_in[5];
    const int* ei_gp_dst = (const int*)d_in[6];
    const int* ei_ps_src = (const int*)d_in[7];
    const int* ei_ps_dst = (const int*)d_in[8];
    const int* ei_sp_src = (const int*)d_in[9];
    const int* ei_sp_dst = (const int*)d_in[10];
    const float* Wl_pg = (const float*)d_in[11];
    const float* bl_pg = (const float*)d_in[12];
    const float* Wr_pg = (const float*)d_in[13];
    const float* Wl_gp = (const float*)d_in[14];
    const float* bl_gp = (const float*)d_in[15];
    const float* Wr_gp = (const float*)d_in[16];
    const float* Wl_ps = (const float*)d_in[17];
    const float* bl_ps = (const float*)d_in[18];
    const float* Wr_ps = (const float*)d_in[19];
    const float* Wl_sp = (const float*)d_in[20];
    const float* bl_sp = (const float*)d_in[21];
    const float* Wr_sp = (const float*)d_in[22];
    const float* W_gw = (const float*)d_in[23];
    const float* b_gw = (const float*)d_in[24];
    const float* W_sw = (const float*)d_in[25];
    const float* b_sw = (const float*)d_in[26];

    float* out  = (float*)d_out;
    float* h_pf = out;                         // 20000*128
    float* o_gw = out + (size_t)N_PFAS * 128;  // 100000
    float* o_sw = o_gw + N_GW;                 // 30000

    char* ws = (char*)d_ws;

#define GRID_GEMM(n) (((n) + 127) / 128)
#define GRID_SCAT(E) (((E) * 32 + 255) / 256)

    // ==================== relation pg: pfas -> gw ====================
    {
        float* bufT = (float*)ws;                                   // 20000*128
        float* bufA = (float*)(ws + (size_t)N_PFAS * 128 * 4);      // 100000*128
        float* cntA = (float*)(ws + (size_t)(N_PFAS + N_GW) * 128 * 4);  // 100000
        gemm_epi<MODE_T><<<GRID_GEMM(N_PFAS), 256, 0, stream>>>(
            N_PFAS, x_pfas, Wl_pg, nullptr, nullptr, nullptr,
            nullptr, nullptr, nullptr, nullptr, bufT);
        hipMemsetAsync(bufA, 0, (size_t)N_GW * 128 * 4, stream);
        hipMemsetAsync(cntA, 0, (size_t)N_GW * 4, stream);
        scatter_kernel<<<GRID_SCAT(E_PG), 256, 0, stream>>>(
            (const float4*)bufT, ei_pg_src, ei_pg_dst, E_PG, bufA, cntA);
        gemm_epi<MODE_SCALAR><<<GRID_GEMM(N_GW), 256, 0, stream>>>(
            N_GW, x_gw, Wr_pg, nullptr, bl_pg, nullptr,
            bufA, cntA, W_gw, b_gw, o_gw);
    }

    // ==================== relation ps: pfas -> sw ====================
    {
        float* bufT = (float*)ws;                                   // 20000*128
        float* bufA = (float*)(ws + (size_t)N_PFAS * 128 * 4);      // 30000*128
        float* cntA = (float*)(ws + (size_t)(N_PFAS + N_SW) * 128 * 4);  // 30000
        gemm_epi<MODE_T><<<GRID_GEMM(N_PFAS), 256, 0, stream>>>(
            N_PFAS, x_pfas, Wl_ps, nullptr, nullptr, nullptr,
            nullptr, nullptr, nullptr, nullptr, bufT);
        hipMemsetAsync(bufA, 0, (size_t)N_SW * 128 * 4, stream);
        hipMemsetAsync(cntA, 0, (size_t)N_SW * 4, stream);
        scatter_kernel<<<GRID_SCAT(E_PS), 256, 0, stream>>>(
            (const float4*)bufT, ei_ps_src, ei_ps_dst, E_PS, bufA, cntA);
        gemm_epi<MODE_SCALAR><<<GRID_GEMM(N_SW), 256, 0, stream>>>(
            N_SW, x_sw, Wr_ps, nullptr, bl_ps, nullptr,
            bufA, cntA, W_sw, b_sw, o_sw);
    }

    // ==================== pfas: base = x @ (WrG + WrS) + blG + blS ====
    gemm_epi<MODE_PF_BASE><<<GRID_GEMM(N_PFAS), 256, 0, stream>>>(
        N_PFAS, x_pfas, Wr_gp, Wr_sp, bl_gp, bl_sp,
        nullptr, nullptr, nullptr, nullptr, h_pf);

    // ==================== relation gp: gw -> pfas ====================
    {
        float* bufT = (float*)ws;                                   // 100000*128
        float* bufA = (float*)(ws + (size_t)N_GW * 128 * 4);        // 20000*128
        float* cntA = (float*)(ws + (size_t)(N_GW + N_PFAS) * 128 * 4); // 20000
        gemm_epi<MODE_T><<<GRID_GEMM(N_GW), 256, 0, stream>>>(
            N_GW, x_gw, Wl_gp, nullptr, nullptr, nullptr,
            nullptr, nullptr, nullptr, nullptr, bufT);
        hipMemsetAsync(bufA, 0, (size_t)N_PFAS * 128 * 4, stream);
        hipMemsetAsync(cntA, 0, (size_t)N_PFAS * 4, stream);
        scatter_kernel<<<GRID_SCAT(E_GP), 256, 0, stream>>>(
            (const float4*)bufT, ei_gp_src, ei_gp_dst, E_GP, bufA, cntA);
        addmean_kernel<<<(N_PFAS * 32 + 255) / 256, 256, 0, stream>>>(
            N_PFAS, bufA, cntA, h_pf, 0);
    }

    // ==================== relation sp: sw -> pfas (+ final relu) ======
    {
        float* bufT = (float*)ws;                                   // 30000*128
        float* bufA = (float*)(ws + (size_t)N_SW * 128 * 4);        // 20000*128
        float* cntA = (float*)(ws + (size_t)(N_SW + N_PFAS) * 128 * 4); // 20000
        gemm_epi<MODE_T><<<GRID_GEMM(N_SW), 256, 0, stream>>>(
            N_SW, x_sw, Wl_sp, nullptr, nullptr, nullptr,
            nullptr, nullptr, nullptr, nullptr, bufT);
        hipMemsetAsync(bufA, 0, (size_t)N_PFAS * 128 * 4, stream);
        hipMemsetAsync(cntA, 0, (size_t)N_PFAS * 4, stream);
        scatter_kernel<<<GRID_SCAT(E_SP), 256, 0, stream>>>(
            (const float4*)bufT, ei_sp_src, ei_sp_dst, E_SP, bufA, cntA);
        addmean_kernel<<<(N_PFAS * 32 + 255) / 256, 256, 0, stream>>>(
            N_PFAS, bufA, cntA, h_pf, 1);
    }

#undef GRID_GEMM
#undef GRID_SCAT
}

// Round 3
// 1587.824 us; speedup vs baseline: 3.5935x; 3.5935x over previous
//
#include <hip/hip_runtime.h>

// ---------------------------------------------------------------------------
// Problem constants
// ---------------------------------------------------------------------------
#define N_PFAS 20000
#define N_GW   100000
#define N_SW   30000
#define E_PG   1600000
#define E_GP   640000
#define E_PS   480000
#define E_SP   320000
// D = OUT = 128 throughout.

// ---------------------------------------------------------------------------
// Shared 128x128 GEMM tile: 256 threads, 128 rows/block, 32-k chunks in LDS.
// Thread (tx=tid&31, ty=tid>>5) accumulates 16 rows x 4 cols.
// acc += X[row0:row0+128, :] @ (Wa (+ Wb))
// ---------------------------------------------------------------------------
__device__ __forceinline__ void tile_gemm_128(
    const float* __restrict__ X, const float* __restrict__ Wa,
    const float* __restrict__ Wb, int n, int row0, int tid,
    float4* sW4, float* sX, float4 acc[16])
{
    const int tx = tid & 31;
    const int ty = tid >> 5;
    const float4* X4 = (const float4*)X;
    const float4* Wa4 = (const float4*)Wa;
    const float4* Wb4 = (const float4*)Wb;

    for (int kc = 0; kc < 4; ++kc) {
        __syncthreads();
        for (int i = tid; i < 1024; i += 256) {
            float4 w = Wa4[kc * 1024 + i];
            if (Wb) {
                float4 b = Wb4[kc * 1024 + i];
                w.x += b.x; w.y += b.y; w.z += b.z; w.w += b.w;
            }
            sW4[i] = w;
        }
        for (int j = tid; j < 1024; j += 256) {
            int rr = j >> 3, k4 = j & 7;
            int r = row0 + rr;
            float4 xv = make_float4(0.f, 0.f, 0.f, 0.f);
            if (r < n) xv = X4[(size_t)r * 32 + kc * 8 + k4];
            int kk = k4 * 4;
            sX[(kk + 0) * 128 + rr] = xv.x;
            sX[(kk + 1) * 128 + rr] = xv.y;
            sX[(kk + 2) * 128 + rr] = xv.z;
            sX[(kk + 3) * 128 + rr] = xv.w;
        }
        __syncthreads();
#pragma unroll 4
        for (int k = 0; k < 32; ++k) {
            float4 w4 = sW4[k * 32 + tx];
            const float4* xr4 = (const float4*)&sX[k * 128 + ty * 16];
#pragma unroll
            for (int q = 0; q < 4; ++q) {
                float4 x4 = xr4[q];
                acc[q * 4 + 0].x += x4.x * w4.x; acc[q * 4 + 0].y += x4.x * w4.y;
                acc[q * 4 + 0].z += x4.x * w4.z; acc[q * 4 + 0].w += x4.x * w4.w;
                acc[q * 4 + 1].x += x4.y * w4.x; acc[q * 4 + 1].y += x4.y * w4.y;
                acc[q * 4 + 1].z += x4.y * w4.z; acc[q * 4 + 1].w += x4.y * w4.w;
                acc[q * 4 + 2].x += x4.z * w4.x; acc[q * 4 + 2].y += x4.z * w4.y;
                acc[q * 4 + 2].z += x4.z * w4.z; acc[q * 4 + 2].w += x4.z * w4.w;
                acc[q * 4 + 3].x += x4.w * w4.x; acc[q * 4 + 3].y += x4.w * w4.y;
                acc[q * 4 + 3].z += x4.w * w4.z; acc[q * 4 + 3].w += x4.w * w4.w;
            }
        }
    }
}

// ---------------------------------------------------------------------------
// bufT = X @ W   (plain transform)
// ---------------------------------------------------------------------------
__global__ __launch_bounds__(256) void gemm_t_kernel(
    int n, const float* __restrict__ X, const float* __restrict__ W,
    float* __restrict__ out)
{
    __shared__ float sW[32 * 128];
    __shared__ float sX[32 * 128];
    const int tid = threadIdx.x;
    const int row0 = blockIdx.x * 128;
    float4 acc[16];
#pragma unroll
    for (int i = 0; i < 16; ++i) acc[i] = make_float4(0.f, 0.f, 0.f, 0.f);
    tile_gemm_128(X, W, nullptr, n, row0, tid, (float4*)sW, sX, acc);

    const int tx = tid & 31;
    const int rbase = row0 + (tid >> 5) * 16;
#pragma unroll
    for (int rr = 0; rr < 16; ++rr) {
        int r = rbase + rr;
        if (r < n) ((float4*)out)[(size_t)r * 32 + tx] = acc[rr];
    }
}

// ---------------------------------------------------------------------------
// gw/sw node pass with fused CSR gather of transformed neighbor rows:
//   h = relu(X@Wr + bl + mean_{CSR}(bufT));  out[r] = h . wout + bout
// ---------------------------------------------------------------------------
__global__ __launch_bounds__(256) void gemm_gather_scalar_kernel(
    int n, const float* __restrict__ X, const float* __restrict__ Wr,
    const float* __restrict__ bl,
    const float* __restrict__ bufT, const int* __restrict__ perm,
    const int* __restrict__ off,
    const float* __restrict__ wout, const float* __restrict__ bout,
    float* __restrict__ out)
{
    __shared__ float sW[32 * 128];
    __shared__ float sX[32 * 128];
    const int tid = threadIdx.x;
    const int row0 = blockIdx.x * 128;
    float4 acc[16];
#pragma unroll
    for (int i = 0; i < 16; ++i) acc[i] = make_float4(0.f, 0.f, 0.f, 0.f);
    tile_gemm_128(X, Wr, nullptr, n, row0, tid, (float4*)sW, sX, acc);

    const int tx = tid & 31;
    const int rbase = row0 + (tid >> 5) * 16;
    const float4* bufT4 = (const float4*)bufT;
    float4 bv = ((const float4*)bl)[tx];
    float4 wo = ((const float4*)wout)[tx];
    float bo = bout[0];

#pragma unroll 1
    for (int rr = 0; rr < 16; ++rr) {
        int r = rbase + rr;
        int lo = 0, hi = 0;
        if (r < n) { lo = off[r]; hi = off[r + 1]; }
        float4 sum = make_float4(0.f, 0.f, 0.f, 0.f);
        for (int i = lo; i < hi; ++i) {
            int s = perm[i];
            float4 v = bufT4[(size_t)s * 32 + tx];
            sum.x += v.x; sum.y += v.y; sum.z += v.z; sum.w += v.w;
        }
        float inv = 1.0f / fmaxf((float)(hi - lo), 1.0f);
        float h0 = fmaxf(acc[rr].x + bv.x + sum.x * inv, 0.f);
        float h1 = fmaxf(acc[rr].y + bv.y + sum.y * inv, 0.f);
        float h2 = fmaxf(acc[rr].z + bv.z + sum.z * inv, 0.f);
        float h3 = fmaxf(acc[rr].w + bv.w + sum.w * inv, 0.f);
        float p = h0 * wo.x + h1 * wo.y + h2 * wo.z + h3 * wo.w;
        p += __shfl_xor(p, 1, 32);
        p += __shfl_xor(p, 2, 32);
        p += __shfl_xor(p, 4, 32);
        p += __shfl_xor(p, 8, 32);
        p += __shfl_xor(p, 16, 32);
        if (tx == 0 && r < n) out[r] = p + bo;
    }
}

// ---------------------------------------------------------------------------
// pfas node pass: h_pf = relu(mean_g@Wl_g + mean_s@Wl_s + x@(WrA+WrB) + blG+blS)
// ---------------------------------------------------------------------------
__global__ __launch_bounds__(256) void gemm_pf3_kernel(
    int n, const float* __restrict__ x,
    const float* __restrict__ WrA, const float* __restrict__ WrB,
    const float* __restrict__ mean_g, const float* __restrict__ Wl_g,
    const float* __restrict__ mean_s, const float* __restrict__ Wl_s,
    const float* __restrict__ blG, const float* __restrict__ blS,
    float* __restrict__ out)
{
    __shared__ float sW[32 * 128];
    __shared__ float sX[32 * 128];
    const int tid = threadIdx.x;
    const int row0 = blockIdx.x * 128;
    float4 acc[16];
#pragma unroll
    for (int i = 0; i < 16; ++i) acc[i] = make_float4(0.f, 0.f, 0.f, 0.f);
    tile_gemm_128(mean_g, Wl_g, nullptr, n, row0, tid, (float4*)sW, sX, acc);
    tile_gemm_128(mean_s, Wl_s, nullptr, n, row0, tid, (float4*)sW, sX, acc);
    tile_gemm_128(x, WrA, WrB, n, row0, tid, (float4*)sW, sX, acc);

    const int tx = tid & 31;
    const int rbase = row0 + (tid >> 5) * 16;
    float4 b1 = ((const float4*)blG)[tx];
    float4 b2 = ((const float4*)blS)[tx];
#pragma unroll
    for (int rr = 0; rr < 16; ++rr) {
        int r = rbase + rr;
        if (r < n) {
            float4 o = acc[rr];
            o.x = fmaxf(o.x + b1.x + b2.x, 0.f);
            o.y = fmaxf(o.y + b1.y + b2.y, 0.f);
            o.z = fmaxf(o.z + b1.z + b2.z, 0.f);
            o.w = fmaxf(o.w + b1.w + b2.w, 0.f);
            ((float4*)out)[(size_t)r * 32 + tx] = o;
        }
    }
}

// ---------------------------------------------------------------------------
// CSR build: histogram -> single-block scan -> permute
// ---------------------------------------------------------------------------
__global__ __launch_bounds__(256) void hist_kernel(
    const int* __restrict__ dst, int E, int* __restrict__ counts)
{
    int e = blockIdx.x * 256 + threadIdx.x;
    if (e < E) atomicAdd(&counts[dst[e]], 1);
}

__global__ __launch_bounds__(1024) void scan_kernel(
    const int* __restrict__ counts, int n,
    int* __restrict__ offsets, int* __restrict__ cursor)
{
    __shared__ int sp[1024];
    const int tid = threadIdx.x;
    const int chunk = (n + 1023) >> 10;
    const int base = tid * chunk;
    int s = 0;
    for (int i = 0; i < chunk; ++i) {
        int idx = base + i;
        if (idx < n) s += counts[idx];
    }
    sp[tid] = s;
    __syncthreads();
    for (int ofs = 1; ofs < 1024; ofs <<= 1) {
        int v = sp[tid];
        int add = (tid >= ofs) ? sp[tid - ofs] : 0;
        __syncthreads();
        sp[tid] = v + add;
        __syncthreads();
    }
    int run = (tid > 0) ? sp[tid - 1] : 0;
    for (int i = 0; i < chunk; ++i) {
        int idx = base + i;
        if (idx < n) {
            offsets[idx] = run;
            cursor[idx] = run;
            run += counts[idx];
        }
    }
    if (tid == 1023) offsets[n] = sp[1023];
}

__global__ __launch_bounds__(256) void permute_kernel(
    const int* __restrict__ src, const int* __restrict__ dst, int E,
    int* __restrict__ cursor, int* __restrict__ perm)
{
    int e = blockIdx.x * 256 + threadIdx.x;
    if (e >= E) return;
    int pos = atomicAdd(&cursor[dst[e]], 1);
    perm[pos] = src[e];
}

// ---------------------------------------------------------------------------
// Segmented mean of RAW source features: one 64-lane wave per dst node.
// Lane handles 2 floats (float2); row = 128 floats = 64 float2.
// ---------------------------------------------------------------------------
__global__ __launch_bounds__(256) void seg_mean_kernel(
    const float2* __restrict__ xsrc, const int* __restrict__ perm,
    const int* __restrict__ off, int n, float2* __restrict__ mean)
{
    int node = blockIdx.x * 4 + (threadIdx.x >> 6);
    if (node >= n) return;
    int lane = threadIdx.x & 63;
    int lo = off[node], hi = off[node + 1];
    float2 acc = make_float2(0.f, 0.f);
    for (int i = lo; i < hi; ++i) {
        int s = perm[i];
        float2 v = xsrc[(size_t)s * 64 + lane];
        acc.x += v.x; acc.y += v.y;
    }
    float inv = 1.0f / fmaxf((float)(hi - lo), 1.0f);
    mean[(size_t)node * 64 + lane] = make_float2(acc.x * inv, acc.y * inv);
}

// ---------------------------------------------------------------------------
// Launch
// ---------------------------------------------------------------------------
extern "C" void kernel_launch(void* const* d_in, const int* in_sizes, int n_in,
                              void* d_out, int out_size, void* d_ws, size_t ws_size,
                              hipStream_t stream)
{
    const float* x_pfas = (const float*)d_in[0];
    const float* x_gw   = (const float*)d_in[1];
    const float* x_sw   = (const float*)d_in[2];
    const int* ei_pg_src = (const int*)d_in[3];
    const int* ei_pg_dst = (const int*)d_in[4];
    const int* ei_gp_src = (const int*)d_in[5];
    const int* ei_gp_dst = (const int*)d_in[6];
    const int* ei_ps_src = (const int*)d_in[7];
    const int* ei_ps_dst = (const int*)d_in[8];
    const int* ei_sp_src = (const int*)d_in[9];
    const int* ei_sp_dst = (const int*)d_in[10];
    const float* Wl_pg = (const float*)d_in[11];
    const float* bl_pg = (const float*)d_in[12];
    const float* Wr_pg = (const float*)d_in[13];
    const float* Wl_gp = (const float*)d_in[14];
    const float* bl_gp = (const float*)d_in[15];
    const float* Wr_gp = (const float*)d_in[16];
    const float* Wl_ps = (const float*)d_in[17];
    const float* bl_ps = (const float*)d_in[18];
    const float* Wr_ps = (const float*)d_in[19];
    const float* Wl_sp = (const float*)d_in[20];
    const float* bl_sp = (const float*)d_in[21];
    const float* Wr_sp = (const float*)d_in[22];
    const float* W_gw = (const float*)d_in[23];
    const float* b_gw = (const float*)d_in[24];
    const float* W_sw = (const float*)d_in[25];
    const float* b_sw = (const float*)d_in[26];

    float* out  = (float*)d_out;
    float* h_pf = out;                         // 20000*128
    float* o_gw = out + (size_t)N_PFAS * 128;  // 100000
    float* o_sw = o_gw + N_GW;                 // 30000

    // ---- workspace layout (~54.6 MB) ----
    char* p = (char*)d_ws;
    auto alloc = [&](size_t bytes) { char* q = p; p += (bytes + 15) & ~(size_t)15; return q; };
    float* bufT_pg = (float*)alloc((size_t)N_PFAS * 128 * 4);
    float* bufT_ps = (float*)alloc((size_t)N_PFAS * 128 * 4);
    float* mean_gp = (float*)alloc((size_t)N_PFAS * 128 * 4);
    float* mean_sp = (float*)alloc((size_t)N_PFAS * 128 * 4);
    int* perm_pg = (int*)alloc((size_t)E_PG * 4);
    int* perm_ps = (int*)alloc((size_t)E_PS * 4);
    int* perm_gp = (int*)alloc((size_t)E_GP * 4);
    int* perm_sp = (int*)alloc((size_t)E_SP * 4);
    int* off_pg = (int*)alloc((size_t)(N_GW + 1) * 4);
    int* off_ps = (int*)alloc((size_t)(N_SW + 1) * 4);
    int* off_gp = (int*)alloc((size_t)(N_PFAS + 1) * 4);
    int* off_sp = (int*)alloc((size_t)(N_PFAS + 1) * 4);
    int* counts = (int*)alloc((size_t)N_GW * 4);   // shared scratch
    int* cursor = (int*)alloc((size_t)N_GW * 4);   // shared scratch

#define GRID_GEMM(n) (((n) + 127) / 128)
#define GRID_E(E)    (((E) + 255) / 256)

    // ---- transforms of the small (pfas) source side ----
    gemm_t_kernel<<<GRID_GEMM(N_PFAS), 256, 0, stream>>>(N_PFAS, x_pfas, Wl_pg, bufT_pg);
    gemm_t_kernel<<<GRID_GEMM(N_PFAS), 256, 0, stream>>>(N_PFAS, x_pfas, Wl_ps, bufT_ps);

    // ---- CSR pg + fused gw pass ----
    hipMemsetAsync(counts, 0, (size_t)N_GW * 4, stream);
    hist_kernel<<<GRID_E(E_PG), 256, 0, stream>>>(ei_pg_dst, E_PG, counts);
    scan_kernel<<<1, 1024, 0, stream>>>(counts, N_GW, off_pg, cursor);
    permute_kernel<<<GRID_E(E_PG), 256, 0, stream>>>(ei_pg_src, ei_pg_dst, E_PG, cursor, perm_pg);
    gemm_gather_scalar_kernel<<<GRID_GEMM(N_GW), 256, 0, stream>>>(
        N_GW, x_gw, Wr_pg, bl_pg, bufT_pg, perm_pg, off_pg, W_gw, b_gw, o_gw);

    // ---- CSR ps + fused sw pass ----
    hipMemsetAsync(counts, 0, (size_t)N_SW * 4, stream);
    hist_kernel<<<GRID_E(E_PS), 256, 0, stream>>>(ei_ps_dst, E_PS, counts);
    scan_kernel<<<1, 1024, 0, stream>>>(counts, N_SW, off_ps, cursor);
    permute_kernel<<<GRID_E(E_PS), 256, 0, stream>>>(ei_ps_src, ei_ps_dst, E_PS, cursor, perm_ps);
    gemm_gather_scalar_kernel<<<GRID_GEMM(N_SW), 256, 0, stream>>>(
        N_SW, x_sw, Wr_ps, bl_ps, bufT_ps, perm_ps, off_ps, W_sw, b_sw, o_sw);

    // ---- CSR gp + raw segmented mean ----
    hipMemsetAsync(counts, 0, (size_t)N_PFAS * 4, stream);
    hist_kernel<<<GRID_E(E_GP), 256, 0, stream>>>(ei_gp_dst, E_GP, counts);
    scan_kernel<<<1, 1024, 0, stream>>>(counts, N_PFAS, off_gp, cursor);
    permute_kernel<<<GRID_E(E_GP), 256, 0, stream>>>(ei_gp_src, ei_gp_dst, E_GP, cursor, perm_gp);
    seg_mean_kernel<<<(N_PFAS + 3) / 4, 256, 0, stream>>>(
        (const float2*)x_gw, perm_gp, off_gp, N_PFAS, (float2*)mean_gp);

    // ---- CSR sp + raw segmented mean ----
    hipMemsetAsync(counts, 0, (size_t)N_PFAS * 4, stream);
    hist_kernel<<<GRID_E(E_SP), 256, 0, stream>>>(ei_sp_dst, E_SP, counts);
    scan_kernel<<<1, 1024, 0, stream>>>(counts, N_PFAS, off_sp, cursor);
    permute_kernel<<<GRID_E(E_SP), 256, 0, stream>>>(ei_sp_src, ei_sp_dst, E_SP, cursor, perm_sp);
    seg_mean_kernel<<<(N_PFAS + 3) / 4, 256, 0, stream>>>(
        (const float2*)x_sw, perm_sp, off_sp, N_PFAS, (float2*)mean_sp);

    // ---- pfas fused node pass ----
    gemm_pf3_kernel<<<GRID_GEMM(N_PFAS), 256, 0, stream>>>(
        N_PFAS, x_pfas, Wr_gp, Wr_sp, mean_gp, Wl_gp, mean_sp, Wl_sp,
        bl_gp, bl_sp, h_pf);

#undef GRID_GEMM
#undef GRID_E
}

// Round 4
// 1195.215 us; speedup vs baseline: 4.7739x; 1.3285x over previous
//
#include <hip/hip_runtime.h>

// ---------------------------------------------------------------------------
// Problem constants
// ---------------------------------------------------------------------------
#define N_PFAS 20000
#define N_GW   100000
#define N_SW   30000
#define E_PG   1600000
#define E_GP   640000
#define E_PS   480000
#define E_SP   320000
#define E_TOT  (E_PG + E_PS + E_GP + E_SP)
// D = OUT = 128 throughout.

// ---------------------------------------------------------------------------
// bf16 helpers (RNE pack, cheap unpack)
// ---------------------------------------------------------------------------
__device__ __forceinline__ unsigned short f2bf(float f) {
    unsigned u = __float_as_uint(f);
    u += 0x7fffu + ((u >> 16) & 1u);
    return (unsigned short)(u >> 16);
}
__device__ __forceinline__ float u2f(unsigned u) { return __uint_as_float(u); }

// ---------------------------------------------------------------------------
// Shared 128x128 GEMM tile: NT threads, 128 rows/block, 32-k chunks in LDS.
// tx=tid&31 (cols 4tx..4tx+3), ty=tid>>5; each ty-group owns RPT=128/(NT/32)
// rows. acc[rr] = row (row0 + ty*RPT + rr).
// acc += X[row0:row0+128, :] @ (Wa (+ Wb))
// ---------------------------------------------------------------------------
template<int NT>
__device__ __forceinline__ void tile_gemm(
    const float* __restrict__ X, const float* __restrict__ Wa,
    const float* __restrict__ Wb, int n, int row0, int tid,
    float4* sW4, float* sX, float4* acc)
{
    constexpr int TY  = NT / 32;
    constexpr int RPT = 128 / TY;
    const int tx = tid & 31;
    const int ty = tid >> 5;
    const float4* X4 = (const float4*)X;
    const float4* Wa4 = (const float4*)Wa;
    const float4* Wb4 = (const float4*)Wb;

    for (int kc = 0; kc < 4; ++kc) {
        __syncthreads();
        for (int i = tid; i < 1024; i += NT) {
            float4 w = Wa4[kc * 1024 + i];
            if (Wb) {
                float4 b = Wb4[kc * 1024 + i];
                w.x += b.x; w.y += b.y; w.z += b.z; w.w += b.w;
            }
            sW4[i] = w;
        }
        for (int j = tid; j < 1024; j += NT) {
            int rr = j >> 3, k4 = j & 7;
            int r = row0 + rr;
            float4 xv = make_float4(0.f, 0.f, 0.f, 0.f);
            if (r < n) xv = X4[(size_t)r * 32 + kc * 8 + k4];
            int kk = k4 * 4;
            sX[(kk + 0) * 128 + rr] = xv.x;
            sX[(kk + 1) * 128 + rr] = xv.y;
            sX[(kk + 2) * 128 + rr] = xv.z;
            sX[(kk + 3) * 128 + rr] = xv.w;
        }
        __syncthreads();
#pragma unroll 4
        for (int k = 0; k < 32; ++k) {
            float4 w4 = sW4[k * 32 + tx];
            const float4* xr4 = (const float4*)&sX[k * 128 + ty * RPT];
#pragma unroll
            for (int q = 0; q < RPT / 4; ++q) {
                float4 x4 = xr4[q];
                acc[q * 4 + 0].x += x4.x * w4.x; acc[q * 4 + 0].y += x4.x * w4.y;
                acc[q * 4 + 0].z += x4.x * w4.z; acc[q * 4 + 0].w += x4.x * w4.w;
                acc[q * 4 + 1].x += x4.y * w4.x; acc[q * 4 + 1].y += x4.y * w4.y;
                acc[q * 4 + 1].z += x4.y * w4.z; acc[q * 4 + 1].w += x4.y * w4.w;
                acc[q * 4 + 2].x += x4.z * w4.x; acc[q * 4 + 2].y += x4.z * w4.y;
                acc[q * 4 + 2].z += x4.z * w4.z; acc[q * 4 + 2].w += x4.z * w4.w;
                acc[q * 4 + 3].x += x4.w * w4.x; acc[q * 4 + 3].y += x4.w * w4.y;
                acc[q * 4 + 3].z += x4.w * w4.z; acc[q * 4 + 3].w += x4.w * w4.w;
            }
        }
    }
}

// ---------------------------------------------------------------------------
// bufT16 = X @ W  (bf16 output). grid.y selects (W0,out0) vs (W1,out1).
// ---------------------------------------------------------------------------
__global__ __launch_bounds__(256) void gemm_t16_kernel(
    int n, const float* __restrict__ X,
    const float* __restrict__ W0, unsigned short* __restrict__ out0,
    const float* __restrict__ W1, unsigned short* __restrict__ out1)
{
    __shared__ float sW[32 * 128];
    __shared__ float sX[32 * 128];
    const int tid = threadIdx.x;
    const int row0 = blockIdx.x * 128;
    const float* W = (blockIdx.y == 0) ? W0 : W1;
    unsigned short* out = (blockIdx.y == 0) ? out0 : out1;

    float4 acc[16];
#pragma unroll
    for (int i = 0; i < 16; ++i) acc[i] = make_float4(0.f, 0.f, 0.f, 0.f);
    tile_gemm<256>(X, W, nullptr, n, row0, tid, (float4*)sW, sX, acc);

    const int tx = tid & 31;
    const int rbase = row0 + (tid >> 5) * 16;
#pragma unroll
    for (int rr = 0; rr < 16; ++rr) {
        int r = rbase + rr;
        if (r < n) {
            uint2 o;
            o.x = (unsigned)f2bf(acc[rr].x) | ((unsigned)f2bf(acc[rr].y) << 16);
            o.y = (unsigned)f2bf(acc[rr].z) | ((unsigned)f2bf(acc[rr].w) << 16);
            *(uint2*)(out + (size_t)r * 128 + tx * 4) = o;
        }
    }
}

// ---------------------------------------------------------------------------
// gw/sw node pass, 512 threads: GEMM X@Wr fused with CSR gather of bf16
// transformed neighbor rows + scalar head.
//   h = relu(X@Wr + bl + mean_{CSR}(bufT16)); out[r] = h . wout + bout
// ---------------------------------------------------------------------------
__global__ __launch_bounds__(512, 8) void gemm_gather_scalar_kernel(
    int n, const float* __restrict__ X, const float* __restrict__ Wr,
    const float* __restrict__ bl,
    const unsigned short* __restrict__ bufT16, const int* __restrict__ perm,
    const int* __restrict__ off,
    const float* __restrict__ wout, const float* __restrict__ bout,
    float* __restrict__ out)
{
    __shared__ float sW[32 * 128];
    __shared__ float sX[32 * 128];
    const int tid = threadIdx.x;
    const int row0 = blockIdx.x * 128;
    float4 acc[8];
#pragma unroll
    for (int i = 0; i < 8; ++i) acc[i] = make_float4(0.f, 0.f, 0.f, 0.f);
    tile_gemm<512>(X, Wr, nullptr, n, row0, tid, (float4*)sW, sX, acc);

    const int tx = tid & 31;
    const int rbase = row0 + (tid >> 5) * 8;
    float4 bv = ((const float4*)bl)[tx];
    float4 wo = ((const float4*)wout)[tx];
    float bo = bout[0];

#pragma unroll 1
    for (int rr = 0; rr < 8; ++rr) {
        int r = rbase + rr;
        int lo = 0, hi = 0;
        if (r < n) { lo = off[r]; hi = off[r + 1]; }
        float4 s0 = make_float4(0.f, 0.f, 0.f, 0.f);
        float4 s1 = make_float4(0.f, 0.f, 0.f, 0.f);
        int i = lo;
        for (; i + 2 <= hi; i += 2) {
            int a = perm[i];
            int b = perm[i + 1];
            uint2 va = *(const uint2*)(bufT16 + (size_t)a * 128 + tx * 4);
            uint2 vb = *(const uint2*)(bufT16 + (size_t)b * 128 + tx * 4);
            s0.x += u2f(va.x << 16); s0.y += u2f(va.x & 0xffff0000u);
            s0.z += u2f(va.y << 16); s0.w += u2f(va.y & 0xffff0000u);
            s1.x += u2f(vb.x << 16); s1.y += u2f(vb.x & 0xffff0000u);
            s1.z += u2f(vb.y << 16); s1.w += u2f(vb.y & 0xffff0000u);
        }
        if (i < hi) {
            int a = perm[i];
            uint2 va = *(const uint2*)(bufT16 + (size_t)a * 128 + tx * 4);
            s0.x += u2f(va.x << 16); s0.y += u2f(va.x & 0xffff0000u);
            s0.z += u2f(va.y << 16); s0.w += u2f(va.y & 0xffff0000u);
        }
        float inv = 1.0f / fmaxf((float)(hi - lo), 1.0f);
        float h0 = fmaxf(acc[rr].x + bv.x + (s0.x + s1.x) * inv, 0.f);
        float h1 = fmaxf(acc[rr].y + bv.y + (s0.y + s1.y) * inv, 0.f);
        float h2 = fmaxf(acc[rr].z + bv.z + (s0.z + s1.z) * inv, 0.f);
        float h3 = fmaxf(acc[rr].w + bv.w + (s0.w + s1.w) * inv, 0.f);
        float p = h0 * wo.x + h1 * wo.y + h2 * wo.z + h3 * wo.w;
        p += __shfl_xor(p, 1, 32);
        p += __shfl_xor(p, 2, 32);
        p += __shfl_xor(p, 4, 32);
        p += __shfl_xor(p, 8, 32);
        p += __shfl_xor(p, 16, 32);
        if (tx == 0 && r < n) out[r] = p + bo;
    }
}

// ---------------------------------------------------------------------------
// pfas node pass: h_pf = relu(mean_g@Wl_g + mean_s@Wl_s + x@(WrA+WrB) + blG+blS)
// ---------------------------------------------------------------------------
__global__ __launch_bounds__(256) void gemm_pf3_kernel(
    int n, const float* __restrict__ x,
    const float* __restrict__ WrA, const float* __restrict__ WrB,
    const float* __restrict__ mean_g, const float* __restrict__ Wl_g,
    const float* __restrict__ mean_s, const float* __restrict__ Wl_s,
    const float* __restrict__ blG, const float* __restrict__ blS,
    float* __restrict__ out)
{
    __shared__ float sW[32 * 128];
    __shared__ float sX[32 * 128];
    const int tid = threadIdx.x;
    const int row0 = blockIdx.x * 128;
    float4 acc[16];
#pragma unroll
    for (int i = 0; i < 16; ++i) acc[i] = make_float4(0.f, 0.f, 0.f, 0.f);
    tile_gemm<256>(mean_g, Wl_g, nullptr, n, row0, tid, (float4*)sW, sX, acc);
    tile_gemm<256>(mean_s, Wl_s, nullptr, n, row0, tid, (float4*)sW, sX, acc);
    tile_gemm<256>(x, WrA, WrB, n, row0, tid, (float4*)sW, sX, acc);

    const int tx = tid & 31;
    const int rbase = row0 + (tid >> 5) * 16;
    float4 b1 = ((const float4*)blG)[tx];
    float4 b2 = ((const float4*)blS)[tx];
#pragma unroll
    for (int rr = 0; rr < 16; ++rr) {
        int r = rbase + rr;
        if (r < n) {
            float4 o = acc[rr];
            o.x = fmaxf(o.x + b1.x + b2.x, 0.f);
            o.y = fmaxf(o.y + b1.y + b2.y, 0.f);
            o.z = fmaxf(o.z + b1.z + b2.z, 0.f);
            o.w = fmaxf(o.w + b1.w + b2.w, 0.f);
            ((float4*)out)[(size_t)r * 32 + tx] = o;
        }
    }
}

// ---------------------------------------------------------------------------
// Fused CSR build for all 4 relations: histogram -> scan(grid=4) -> permute
// ---------------------------------------------------------------------------
__global__ __launch_bounds__(256) void hist_all_kernel(
    const int* __restrict__ d_pg, const int* __restrict__ d_ps,
    const int* __restrict__ d_gp, const int* __restrict__ d_sp,
    int* __restrict__ c_pg, int* __restrict__ c_ps,
    int* __restrict__ c_gp, int* __restrict__ c_sp)
{
    int e = blockIdx.x * 256 + threadIdx.x;
    if (e < E_PG) atomicAdd(&c_pg[d_pg[e]], 1);
    else if (e < E_PG + E_PS) atomicAdd(&c_ps[d_ps[e - E_PG]], 1);
    else if (e < E_PG + E_PS + E_GP) atomicAdd(&c_gp[d_gp[e - E_PG - E_PS]], 1);
    else if (e < E_TOT) atomicAdd(&c_sp[d_sp[e - E_PG - E_PS - E_GP]], 1);
}

__global__ __launch_bounds__(1024) void scan_all_kernel(
    const int* __restrict__ c_pg, const int* __restrict__ c_ps,
    const int* __restrict__ c_gp, const int* __restrict__ c_sp,
    int* __restrict__ off_pg, int* __restrict__ off_ps,
    int* __restrict__ off_gp, int* __restrict__ off_sp,
    int* __restrict__ cur_pg, int* __restrict__ cur_ps,
    int* __restrict__ cur_gp, int* __restrict__ cur_sp)
{
    __shared__ int sp[1024];
    const int tid = threadIdx.x;
    const int rel = blockIdx.x;
    const int* counts; int n; int* offsets; int* cursor;
    if (rel == 0)      { counts = c_pg; n = N_GW;   offsets = off_pg; cursor = cur_pg; }
    else if (rel == 1) { counts = c_ps; n = N_SW;   offsets = off_ps; cursor = cur_ps; }
    else if (rel == 2) { counts = c_gp; n = N_PFAS; offsets = off_gp; cursor = cur_gp; }
    else               { counts = c_sp; n = N_PFAS; offsets = off_sp; cursor = cur_sp; }

    const int chunk = (n + 1023) >> 10;
    const int base = tid * chunk;
    int s = 0;
    for (int i = 0; i < chunk; ++i) {
        int idx = base + i;
        if (idx < n) s += counts[idx];
    }
    sp[tid] = s;
    __syncthreads();
    for (int ofs = 1; ofs < 1024; ofs <<= 1) {
        int v = sp[tid];
        int add = (tid >= ofs) ? sp[tid - ofs] : 0;
        __syncthreads();
        sp[tid] = v + add;
        __syncthreads();
    }
    int run = (tid > 0) ? sp[tid - 1] : 0;
    for (int i = 0; i < chunk; ++i) {
        int idx = base + i;
        if (idx < n) {
            offsets[idx] = run;
            cursor[idx] = run;
            run += counts[idx];
        }
    }
    if (tid == 1023) offsets[n] = sp[1023];
}

__global__ __launch_bounds__(256) void permute_all_kernel(
    const int* __restrict__ s_pg, const int* __restrict__ d_pg,
    const int* __restrict__ s_ps, const int* __restrict__ d_ps,
    const int* __restrict__ s_gp, const int* __restrict__ d_gp,
    const int* __restrict__ s_sp, const int* __restrict__ d_sp,
    int* __restrict__ cur_pg, int* __restrict__ cur_ps,
    int* __restrict__ cur_gp, int* __restrict__ cur_sp,
    int* __restrict__ p_pg, int* __restrict__ p_ps,
    int* __restrict__ p_gp, int* __restrict__ p_sp)
{
    int e = blockIdx.x * 256 + threadIdx.x;
    if (e < E_PG) {
        int pos = atomicAdd(&cur_pg[d_pg[e]], 1);
        p_pg[pos] = s_pg[e];
    } else if (e < E_PG + E_PS) {
        int i = e - E_PG;
        int pos = atomicAdd(&cur_ps[d_ps[i]], 1);
        p_ps[pos] = s_ps[i];
    } else if (e < E_PG + E_PS + E_GP) {
        int i = e - E_PG - E_PS;
        int pos = atomicAdd(&cur_gp[d_gp[i]], 1);
        p_gp[pos] = s_gp[i];
    } else if (e < E_TOT) {
        int i = e - E_PG - E_PS - E_GP;
        int pos = atomicAdd(&cur_sp[d_sp[i]], 1);
        p_sp[pos] = s_sp[i];
    }
}

// ---------------------------------------------------------------------------
// Segmented mean of raw fp32 source features: one 64-lane wave per dst node,
// lane = float2. grid.y selects relation (gp vs sp).
// ---------------------------------------------------------------------------
__global__ __launch_bounds__(256) void seg_mean_kernel(
    const float2* __restrict__ x0, const int* __restrict__ perm0,
    const int* __restrict__ off0, float2* __restrict__ mean0,
    const float2* __restrict__ x1, const int* __restrict__ perm1,
    const int* __restrict__ off1, float2* __restrict__ mean1, int n)
{
    const float2* xsrc; const int* perm; const int* off; float2* mean;
    if (blockIdx.y == 0) { xsrc = x0; perm = perm0; off = off0; mean = mean0; }
    else                 { xsrc = x1; perm = perm1; off = off1; mean = mean1; }

    int node = blockIdx.x * 4 + (threadIdx.x >> 6);
    if (node >= n) return;
    int lane = threadIdx.x & 63;
    int lo = off[node], hi = off[node + 1];
    float2 a0 = make_float2(0.f, 0.f);
    float2 a1 = make_float2(0.f, 0.f);
    int i = lo;
    for (; i + 2 <= hi; i += 2) {
        int sa = perm[i];
        int sb = perm[i + 1];
        float2 va = xsrc[(size_t)sa * 64 + lane];
        float2 vb = xsrc[(size_t)sb * 64 + lane];
        a0.x += va.x; a0.y += va.y;
        a1.x += vb.x; a1.y += vb.y;
    }
    if (i < hi) {
        int sa = perm[i];
        float2 va = xsrc[(size_t)sa * 64 + lane];
        a0.x += va.x; a0.y += va.y;
    }
    float inv = 1.0f / fmaxf((float)(hi - lo), 1.0f);
    mean[(size_t)node * 64 + lane] = make_float2((a0.x + a1.x) * inv, (a0.y + a1.y) * inv);
}

// ---------------------------------------------------------------------------
// Launch
// ---------------------------------------------------------------------------
extern "C" void kernel_launch(void* const* d_in, const int* in_sizes, int n_in,
                              void* d_out, int out_size, void* d_ws, size_t ws_size,
                              hipStream_t stream)
{
    const float* x_pfas = (const float*)d_in[0];
    const float* x_gw   = (const float*)d_in[1];
    const float* x_sw   = (const float*)d_in[2];
    const int* ei_pg_src = (const int*)d_in[3];
    const int* ei_pg_dst = (const int*)d_in[4];
    const int* ei_gp_src = (const int*)d_in[5];
    const int* ei_gp_dst = (const int*)d_in[6];
    const int* ei_ps_src = (const int*)d_in[7];
    const int* ei_ps_dst = (const int*)d_in[8];
    const int* ei_sp_src = (const int*)d_in[9];
    const int* ei_sp_dst = (const int*)d_in[10];
    const float* Wl_pg = (const float*)d_in[11];
    const float* bl_pg = (const float*)d_in[12];
    const float* Wr_pg = (const float*)d_in[13];
    const float* Wl_gp = (const float*)d_in[14];
    const float* bl_gp = (const float*)d_in[15];
    const float* Wr_gp = (const float*)d_in[16];
    const float* Wl_ps = (const float*)d_in[17];
    const float* bl_ps = (const float*)d_in[18];
    const float* Wr_ps = (const float*)d_in[19];
    const float* Wl_sp = (const float*)d_in[20];
    const float* bl_sp = (const float*)d_in[21];
    const float* Wr_sp = (const float*)d_in[22];
    const float* W_gw = (const float*)d_in[23];
    const float* b_gw = (const float*)d_in[24];
    const float* W_sw = (const float*)d_in[25];
    const float* b_sw = (const float*)d_in[26];

    float* out  = (float*)d_out;
    float* h_pf = out;                         // 20000*128
    float* o_gw = out + (size_t)N_PFAS * 128;  // 100000
    float* o_sw = o_gw + N_GW;                 // 30000

    // ---- workspace layout (~45 MB) ----
    char* p = (char*)d_ws;
    auto alloc = [&](size_t bytes) { char* q = p; p += (bytes + 15) & ~(size_t)15; return q; };
    unsigned short* bufT_pg = (unsigned short*)alloc((size_t)N_PFAS * 128 * 2);
    unsigned short* bufT_ps = (unsigned short*)alloc((size_t)N_PFAS * 128 * 2);
    float* mean_gp = (float*)alloc((size_t)N_PFAS * 128 * 4);
    float* mean_sp = (float*)alloc((size_t)N_PFAS * 128 * 4);
    int* perm_pg = (int*)alloc((size_t)E_PG * 4);
    int* perm_ps = (int*)alloc((size_t)E_PS * 4);
    int* perm_gp = (int*)alloc((size_t)E_GP * 4);
    int* perm_sp = (int*)alloc((size_t)E_SP * 4);
    int* off_pg = (int*)alloc((size_t)(N_GW + 1) * 4);
    int* off_ps = (int*)alloc((size_t)(N_SW + 1) * 4);
    int* off_gp = (int*)alloc((size_t)(N_PFAS + 1) * 4);
    int* off_sp = (int*)alloc((size_t)(N_PFAS + 1) * 4);
    int* counts = (int*)alloc((size_t)(N_GW + N_SW + 2 * N_PFAS) * 4);
    int* cursor = (int*)alloc((size_t)(N_GW + N_SW + 2 * N_PFAS) * 4);
    int* c_pg = counts;
    int* c_ps = counts + N_GW;
    int* c_gp = c_ps + N_SW;
    int* c_sp = c_gp + N_PFAS;
    int* u_pg = cursor;
    int* u_ps = cursor + N_GW;
    int* u_gp = u_ps + N_SW;
    int* u_sp = u_gp + N_PFAS;

    // ---- 1. transforms of the pfas source side (bf16 out) ----
    dim3 gT((N_PFAS + 127) / 128, 2);
    gemm_t16_kernel<<<gT, 256, 0, stream>>>(
        N_PFAS, x_pfas, Wl_pg, bufT_pg, Wl_ps, bufT_ps);

    // ---- 2. fused CSR build for all relations ----
    hipMemsetAsync(counts, 0, (size_t)(N_GW + N_SW + 2 * N_PFAS) * 4, stream);
    hist_all_kernel<<<(E_TOT + 255) / 256, 256, 0, stream>>>(
        ei_pg_dst, ei_ps_dst, ei_gp_dst, ei_sp_dst, c_pg, c_ps, c_gp, c_sp);
    scan_all_kernel<<<4, 1024, 0, stream>>>(
        c_pg, c_ps, c_gp, c_sp, off_pg, off_ps, off_gp, off_sp,
        u_pg, u_ps, u_gp, u_sp);
    permute_all_kernel<<<(E_TOT + 255) / 256, 256, 0, stream>>>(
        ei_pg_src, ei_pg_dst, ei_ps_src, ei_ps_dst,
        ei_gp_src, ei_gp_dst, ei_sp_src, ei_sp_dst,
        u_pg, u_ps, u_gp, u_sp, perm_pg, perm_ps, perm_gp, perm_sp);

    // ---- 3. gw / sw fused node passes ----
    gemm_gather_scalar_kernel<<<(N_GW + 127) / 128, 512, 0, stream>>>(
        N_GW, x_gw, Wr_pg, bl_pg, bufT_pg, perm_pg, off_pg, W_gw, b_gw, o_gw);
    gemm_gather_scalar_kernel<<<(N_SW + 127) / 128, 512, 0, stream>>>(
        N_SW, x_sw, Wr_ps, bl_ps, bufT_ps, perm_ps, off_ps, W_sw, b_sw, o_sw);

    // ---- 4. raw segmented means into pfas ----
    dim3 gM((N_PFAS + 3) / 4, 2);
    seg_mean_kernel<<<gM, 256, 0, stream>>>(
        (const float2*)x_gw, perm_gp, off_gp, (float2*)mean_gp,
        (const float2*)x_sw, perm_sp, off_sp, (float2*)mean_sp, N_PFAS);

    // ---- 5. pfas fused node pass ----
    gemm_pf3_kernel<<<(N_PFAS + 127) / 128, 256, 0, stream>>>(
        N_PFAS, x_pfas, Wr_gp, Wr_sp, mean_gp, Wl_gp, mean_sp, Wl_sp,
        bl_gp, bl_sp, h_pf);
}

// Round 5
// 932.548 us; speedup vs baseline: 6.1185x; 1.2817x over previous
//
#include <hip/hip_runtime.h>

// ---------------------------------------------------------------------------
// Problem constants
// ---------------------------------------------------------------------------
#define N_PFAS 20000
#define N_GW   100000
#define N_SW   30000
#define E_PG   1600000
#define E_GP   640000
#define E_PS   480000
#define E_SP   320000
#define E_TOT  (E_PG + E_PS + E_GP + E_SP)
// Concatenated node-count layout: [pg: N_GW][ps: N_SW][gp: N_PFAS][sp: N_PFAS]
#define BASE_PG 0
#define BASE_PS (N_GW)
#define BASE_GP (N_GW + N_SW)
#define BASE_SP (N_GW + N_SW + N_PFAS)
#define NTOT    (N_GW + N_SW + 2 * N_PFAS)
// Edge-range bases in perm_all (guaranteed by global scan over concat counts):
//   pg: [0, E_PG), ps: [E_PG, ..), gp: .., sp: .. ending at E_TOT.
#define SCAN_NBLK ((NTOT + 2047) / 2048)

// ---------------------------------------------------------------------------
// bf16 helpers (RNE pack, cheap unpack)
// ---------------------------------------------------------------------------
__device__ __forceinline__ unsigned short f2bf(float f) {
    unsigned u = __float_as_uint(f);
    u += 0x7fffu + ((u >> 16) & 1u);
    return (unsigned short)(u >> 16);
}
__device__ __forceinline__ float u2f(unsigned u) { return __uint_as_float(u); }

// ---------------------------------------------------------------------------
// Shared 128x128 GEMM tile: NT threads, 128 rows/block, 32-k chunks in LDS.
// ---------------------------------------------------------------------------
template<int NT>
__device__ __forceinline__ void tile_gemm(
    const float* __restrict__ X, const float* __restrict__ Wa,
    const float* __restrict__ Wb, int n, int row0, int tid,
    float4* sW4, float* sX, float4* acc)
{
    constexpr int TY  = NT / 32;
    constexpr int RPT = 128 / TY;
    const int tx = tid & 31;
    const int ty = tid >> 5;
    const float4* X4 = (const float4*)X;
    const float4* Wa4 = (const float4*)Wa;
    const float4* Wb4 = (const float4*)Wb;

    for (int kc = 0; kc < 4; ++kc) {
        __syncthreads();
        for (int i = tid; i < 1024; i += NT) {
            float4 w = Wa4[kc * 1024 + i];
            if (Wb) {
                float4 b = Wb4[kc * 1024 + i];
                w.x += b.x; w.y += b.y; w.z += b.z; w.w += b.w;
            }
            sW4[i] = w;
        }
        for (int j = tid; j < 1024; j += NT) {
            int rr = j >> 3, k4 = j & 7;
            int r = row0 + rr;
            float4 xv = make_float4(0.f, 0.f, 0.f, 0.f);
            if (r < n) xv = X4[(size_t)r * 32 + kc * 8 + k4];
            int kk = k4 * 4;
            sX[(kk + 0) * 128 + rr] = xv.x;
            sX[(kk + 1) * 128 + rr] = xv.y;
            sX[(kk + 2) * 128 + rr] = xv.z;
            sX[(kk + 3) * 128 + rr] = xv.w;
        }
        __syncthreads();
#pragma unroll 4
        for (int k = 0; k < 32; ++k) {
            float4 w4 = sW4[k * 32 + tx];
            const float4* xr4 = (const float4*)&sX[k * 128 + ty * RPT];
#pragma unroll
            for (int q = 0; q < RPT / 4; ++q) {
                float4 x4 = xr4[q];
                acc[q * 4 + 0].x += x4.x * w4.x; acc[q * 4 + 0].y += x4.x * w4.y;
                acc[q * 4 + 0].z += x4.x * w4.z; acc[q * 4 + 0].w += x4.x * w4.w;
                acc[q * 4 + 1].x += x4.y * w4.x; acc[q * 4 + 1].y += x4.y * w4.y;
                acc[q * 4 + 1].z += x4.y * w4.z; acc[q * 4 + 1].w += x4.y * w4.w;
                acc[q * 4 + 2].x += x4.z * w4.x; acc[q * 4 + 2].y += x4.z * w4.y;
                acc[q * 4 + 2].z += x4.z * w4.z; acc[q * 4 + 2].w += x4.z * w4.w;
                acc[q * 4 + 3].x += x4.w * w4.x; acc[q * 4 + 3].y += x4.w * w4.y;
                acc[q * 4 + 3].z += x4.w * w4.z; acc[q * 4 + 3].w += x4.w * w4.w;
            }
        }
    }
}

// ---------------------------------------------------------------------------
// bufT16 = X @ W  (bf16 output). grid.y selects (W0,out0) vs (W1,out1).
// ---------------------------------------------------------------------------
__global__ __launch_bounds__(256) void gemm_t16_kernel(
    int n, const float* __restrict__ X,
    const float* __restrict__ W0, unsigned short* __restrict__ out0,
    const float* __restrict__ W1, unsigned short* __restrict__ out1)
{
    __shared__ float sW[32 * 128];
    __shared__ float sX[32 * 128];
    const int tid = threadIdx.x;
    const int row0 = blockIdx.x * 128;
    const float* W = (blockIdx.y == 0) ? W0 : W1;
    unsigned short* out = (blockIdx.y == 0) ? out0 : out1;

    float4 acc[16];
#pragma unroll
    for (int i = 0; i < 16; ++i) acc[i] = make_float4(0.f, 0.f, 0.f, 0.f);
    tile_gemm<256>(X, W, nullptr, n, row0, tid, (float4*)sW, sX, acc);

    const int tx = tid & 31;
    const int rbase = row0 + (tid >> 5) * 16;
#pragma unroll
    for (int rr = 0; rr < 16; ++rr) {
        int r = rbase + rr;
        if (r < n) {
            uint2 o;
            o.x = (unsigned)f2bf(acc[rr].x) | ((unsigned)f2bf(acc[rr].y) << 16);
            o.y = (unsigned)f2bf(acc[rr].z) | ((unsigned)f2bf(acc[rr].w) << 16);
            *(uint2*)(out + (size_t)r * 128 + tx * 4) = o;
        }
    }
}

// ---------------------------------------------------------------------------
// gw/sw node pass, 512 threads: GEMM X@Wr fused with CSR gather of bf16
// transformed neighbor rows + scalar head.
// ---------------------------------------------------------------------------
__global__ __launch_bounds__(512, 8) void gemm_gather_scalar_kernel(
    int n, const float* __restrict__ X, const float* __restrict__ Wr,
    const float* __restrict__ bl,
    const unsigned short* __restrict__ bufT16, const int* __restrict__ perm,
    const int* __restrict__ off,
    const float* __restrict__ wout, const float* __restrict__ bout,
    float* __restrict__ out)
{
    __shared__ float sW[32 * 128];
    __shared__ float sX[32 * 128];
    const int tid = threadIdx.x;
    const int row0 = blockIdx.x * 128;
    float4 acc[8];
#pragma unroll
    for (int i = 0; i < 8; ++i) acc[i] = make_float4(0.f, 0.f, 0.f, 0.f);
    tile_gemm<512>(X, Wr, nullptr, n, row0, tid, (float4*)sW, sX, acc);

    const int tx = tid & 31;
    const int rbase = row0 + (tid >> 5) * 8;
    float4 bv = ((const float4*)bl)[tx];
    float4 wo = ((const float4*)wout)[tx];
    float bo = bout[0];

#pragma unroll 1
    for (int rr = 0; rr < 8; ++rr) {
        int r = rbase + rr;
        int lo = 0, hi = 0;
        if (r < n) { lo = off[r]; hi = off[r + 1]; }
        float4 s0 = make_float4(0.f, 0.f, 0.f, 0.f);
        float4 s1 = make_float4(0.f, 0.f, 0.f, 0.f);
        int i = lo;
        for (; i + 2 <= hi; i += 2) {
            int a = perm[i];
            int b = perm[i + 1];
            uint2 va = *(const uint2*)(bufT16 + (size_t)a * 128 + tx * 4);
            uint2 vb = *(const uint2*)(bufT16 + (size_t)b * 128 + tx * 4);
            s0.x += u2f(va.x << 16); s0.y += u2f(va.x & 0xffff0000u);
            s0.z += u2f(va.y << 16); s0.w += u2f(va.y & 0xffff0000u);
            s1.x += u2f(vb.x << 16); s1.y += u2f(vb.x & 0xffff0000u);
            s1.z += u2f(vb.y << 16); s1.w += u2f(vb.y & 0xffff0000u);
        }
        if (i < hi) {
            int a = perm[i];
            uint2 va = *(const uint2*)(bufT16 + (size_t)a * 128 + tx * 4);
            s0.x += u2f(va.x << 16); s0.y += u2f(va.x & 0xffff0000u);
            s0.z += u2f(va.y << 16); s0.w += u2f(va.y & 0xffff0000u);
        }
        float inv = 1.0f / fmaxf((float)(hi - lo), 1.0f);
        float h0 = fmaxf(acc[rr].x + bv.x + (s0.x + s1.x) * inv, 0.f);
        float h1 = fmaxf(acc[rr].y + bv.y + (s0.y + s1.y) * inv, 0.f);
        float h2 = fmaxf(acc[rr].z + bv.z + (s0.z + s1.z) * inv, 0.f);
        float h3 = fmaxf(acc[rr].w + bv.w + (s0.w + s1.w) * inv, 0.f);
        float p = h0 * wo.x + h1 * wo.y + h2 * wo.z + h3 * wo.w;
        p += __shfl_xor(p, 1, 32);
        p += __shfl_xor(p, 2, 32);
        p += __shfl_xor(p, 4, 32);
        p += __shfl_xor(p, 8, 32);
        p += __shfl_xor(p, 16, 32);
        if (tx == 0 && r < n) out[r] = p + bo;
    }
}

// ---------------------------------------------------------------------------
// pfas node pass: h_pf = relu(mean_g@Wl_g + mean_s@Wl_s + x@(WrA+WrB) + blG+blS)
// ---------------------------------------------------------------------------
__global__ __launch_bounds__(256) void gemm_pf3_kernel(
    int n, const float* __restrict__ x,
    const float* __restrict__ WrA, const float* __restrict__ WrB,
    const float* __restrict__ mean_g, const float* __restrict__ Wl_g,
    const float* __restrict__ mean_s, const float* __restrict__ Wl_s,
    const float* __restrict__ blG, const float* __restrict__ blS,
    float* __restrict__ out)
{
    __shared__ float sW[32 * 128];
    __shared__ float sX[32 * 128];
    const int tid = threadIdx.x;
    const int row0 = blockIdx.x * 128;
    float4 acc[16];
#pragma unroll
    for (int i = 0; i < 16; ++i) acc[i] = make_float4(0.f, 0.f, 0.f, 0.f);
    tile_gemm<256>(mean_g, Wl_g, nullptr, n, row0, tid, (float4*)sW, sX, acc);
    tile_gemm<256>(mean_s, Wl_s, nullptr, n, row0, tid, (float4*)sW, sX, acc);
    tile_gemm<256>(x, WrA, WrB, n, row0, tid, (float4*)sW, sX, acc);

    const int tx = tid & 31;
    const int rbase = row0 + (tid >> 5) * 16;
    float4 b1 = ((const float4*)blG)[tx];
    float4 b2 = ((const float4*)blS)[tx];
#pragma unroll
    for (int rr = 0; rr < 16; ++rr) {
        int r = rbase + rr;
        if (r < n) {
            float4 o = acc[rr];
            o.x = fmaxf(o.x + b1.x + b2.x, 0.f);
            o.y = fmaxf(o.y + b1.y + b2.y, 0.f);
            o.z = fmaxf(o.z + b1.z + b2.z, 0.f);
            o.w = fmaxf(o.w + b1.w + b2.w, 0.f);
            ((float4*)out)[(size_t)r * 32 + tx] = o;
        }
    }
}

// ---------------------------------------------------------------------------
// Histogram into concatenated counts array.
// ---------------------------------------------------------------------------
__global__ __launch_bounds__(256) void hist_all_kernel(
    const int* __restrict__ d_pg, const int* __restrict__ d_ps,
    const int* __restrict__ d_gp, const int* __restrict__ d_sp,
    int* __restrict__ counts)
{
    int e = blockIdx.x * 256 + threadIdx.x;
    if (e < E_PG) atomicAdd(&counts[BASE_PG + d_pg[e]], 1);
    else if (e < E_PG + E_PS) atomicAdd(&counts[BASE_PS + d_ps[e - E_PG]], 1);
    else if (e < E_PG + E_PS + E_GP) atomicAdd(&counts[BASE_GP + d_gp[e - E_PG - E_PS]], 1);
    else if (e < E_TOT) atomicAdd(&counts[BASE_SP + d_sp[e - E_PG - E_PS - E_GP]], 1);
}

// ---------------------------------------------------------------------------
// 3-phase global exclusive scan over NTOT concatenated counts.
// Phase A: per-block sums (2048 elems/block, coalesced).
// ---------------------------------------------------------------------------
__global__ __launch_bounds__(256) void scanA_kernel(
    const int* __restrict__ counts, int* __restrict__ blockSums)
{
    __shared__ int red[256];
    int base = blockIdx.x * 2048;
    int s = 0;
#pragma unroll
    for (int i = 0; i < 8; ++i) {
        int idx = base + i * 256 + threadIdx.x;
        if (idx < NTOT) s += counts[idx];
    }
    red[threadIdx.x] = s;
    __syncthreads();
    for (int ofs = 128; ofs > 0; ofs >>= 1) {
        if (threadIdx.x < ofs) red[threadIdx.x] += red[threadIdx.x + ofs];
        __syncthreads();
    }
    if (threadIdx.x == 0) blockSums[blockIdx.x] = red[0];
}

// Phase B: single small block scans the 84 block sums (exclusive, in place).
__global__ __launch_bounds__(128) void scanB_kernel(
    int* __restrict__ blockSums, int* __restrict__ off_all)
{
    __shared__ int sp[128];
    int t = threadIdx.x;
    int v = (t < SCAN_NBLK) ? blockSums[t] : 0;
    sp[t] = v;
    __syncthreads();
    for (int ofs = 1; ofs < 128; ofs <<= 1) {
        int add = (t >= ofs) ? sp[t - ofs] : 0;
        __syncthreads();
        sp[t] += add;
        __syncthreads();
    }
    if (t < SCAN_NBLK) blockSums[t] = sp[t] - v;   // exclusive prefix
    if (t == 0) off_all[NTOT] = E_TOT;
}

// Phase C: each block rescans its 2048 counts, writes off_all & cursor_all.
__global__ __launch_bounds__(256) void scanC_kernel(
    const int* __restrict__ counts, const int* __restrict__ blockSums,
    int* __restrict__ off_all, int* __restrict__ cursor_all)
{
    __shared__ int sp[256];
    const int t = threadIdx.x;
    const int myBase = blockIdx.x * 2048 + t * 8;
    int c[8];
    int s = 0;
#pragma unroll
    for (int i = 0; i < 8; ++i) {
        int idx = myBase + i;
        c[i] = (idx < NTOT) ? counts[idx] : 0;
        s += c[i];
    }
    sp[t] = s;
    __syncthreads();
    for (int ofs = 1; ofs < 256; ofs <<= 1) {
        int add = (t >= ofs) ? sp[t - ofs] : 0;
        __syncthreads();
        sp[t] += add;
        __syncthreads();
    }
    int run = blockSums[blockIdx.x] + sp[t] - s;
#pragma unroll
    for (int i = 0; i < 8; ++i) {
        int idx = myBase + i;
        if (idx < NTOT) { off_all[idx] = run; cursor_all[idx] = run; }
        run += c[i];
    }
}

// ---------------------------------------------------------------------------
// Permute all relations into one concatenated perm_all via cursor_all.
// ---------------------------------------------------------------------------
__global__ __launch_bounds__(256) void permute_all_kernel(
    const int* __restrict__ s_pg, const int* __restrict__ d_pg,
    const int* __restrict__ s_ps, const int* __restrict__ d_ps,
    const int* __restrict__ s_gp, const int* __restrict__ d_gp,
    const int* __restrict__ s_sp, const int* __restrict__ d_sp,
    int* __restrict__ cursor_all, int* __restrict__ perm_all)
{
    int e = blockIdx.x * 256 + threadIdx.x;
    if (e < E_PG) {
        int pos = atomicAdd(&cursor_all[BASE_PG + d_pg[e]], 1);
        perm_all[pos] = s_pg[e];
    } else if (e < E_PG + E_PS) {
        int i = e - E_PG;
        int pos = atomicAdd(&cursor_all[BASE_PS + d_ps[i]], 1);
        perm_all[pos] = s_ps[i];
    } else if (e < E_PG + E_PS + E_GP) {
        int i = e - E_PG - E_PS;
        int pos = atomicAdd(&cursor_all[BASE_GP + d_gp[i]], 1);
        perm_all[pos] = s_gp[i];
    } else if (e < E_TOT) {
        int i = e - E_PG - E_PS - E_GP;
        int pos = atomicAdd(&cursor_all[BASE_SP + d_sp[i]], 1);
        perm_all[pos] = s_sp[i];
    }
}

// ---------------------------------------------------------------------------
// Segmented mean of raw fp32 source features: one 64-lane wave per dst node.
// grid.y selects relation (gp vs sp).
// ---------------------------------------------------------------------------
__global__ __launch_bounds__(256) void seg_mean_kernel(
    const float2* __restrict__ x0, const int* __restrict__ off0,
    float2* __restrict__ mean0,
    const float2* __restrict__ x1, const int* __restrict__ off1,
    float2* __restrict__ mean1,
    const int* __restrict__ perm_all, int n)
{
    const float2* xsrc; const int* off; float2* mean;
    if (blockIdx.y == 0) { xsrc = x0; off = off0; mean = mean0; }
    else                 { xsrc = x1; off = off1; mean = mean1; }

    int node = blockIdx.x * 4 + (threadIdx.x >> 6);
    if (node >= n) return;
    int lane = threadIdx.x & 63;
    int lo = off[node], hi = off[node + 1];
    float2 a0 = make_float2(0.f, 0.f);
    float2 a1 = make_float2(0.f, 0.f);
    int i = lo;
    for (; i + 2 <= hi; i += 2) {
        int sa = perm_all[i];
        int sb = perm_all[i + 1];
        float2 va = xsrc[(size_t)sa * 64 + lane];
        float2 vb = xsrc[(size_t)sb * 64 + lane];
        a0.x += va.x; a0.y += va.y;
        a1.x += vb.x; a1.y += vb.y;
    }
    if (i < hi) {
        int sa = perm_all[i];
        float2 va = xsrc[(size_t)sa * 64 + lane];
        a0.x += va.x; a0.y += va.y;
    }
    float inv = 1.0f / fmaxf((float)(hi - lo), 1.0f);
    mean[(size_t)node * 64 + lane] = make_float2((a0.x + a1.x) * inv, (a0.y + a1.y) * inv);
}

// ---------------------------------------------------------------------------
// Launch
// ---------------------------------------------------------------------------
extern "C" void kernel_launch(void* const* d_in, const int* in_sizes, int n_in,
                              void* d_out, int out_size, void* d_ws, size_t ws_size,
                              hipStream_t stream)
{
    const float* x_pfas = (const float*)d_in[0];
    const float* x_gw   = (const float*)d_in[1];
    const float* x_sw   = (const float*)d_in[2];
    const int* ei_pg_src = (const int*)d_in[3];
    const int* ei_pg_dst = (const int*)d_in[4];
    const int* ei_gp_src = (const int*)d_in[5];
    const int* ei_gp_dst = (const int*)d_in[6];
    const int* ei_ps_src = (const int*)d_in[7];
    const int* ei_ps_dst = (const int*)d_in[8];
    const int* ei_sp_src = (const int*)d_in[9];
    const int* ei_sp_dst = (const int*)d_in[10];
    const float* Wl_pg = (const float*)d_in[11];
    const float* bl_pg = (const float*)d_in[12];
    const float* Wr_pg = (const float*)d_in[13];
    const float* Wl_gp = (const float*)d_in[14];
    const float* bl_gp = (const float*)d_in[15];
    const float* Wr_gp = (const float*)d_in[16];
    const float* Wl_ps = (const float*)d_in[17];
    const float* bl_ps = (const float*)d_in[18];
    const float* Wr_ps = (const float*)d_in[19];
    const float* Wl_sp = (const float*)d_in[20];
    const float* bl_sp = (const float*)d_in[21];
    const float* Wr_sp = (const float*)d_in[22];
    const float* W_gw = (const float*)d_in[23];
    const float* b_gw = (const float*)d_in[24];
    const float* W_sw = (const float*)d_in[25];
    const float* b_sw = (const float*)d_in[26];

    float* out  = (float*)d_out;
    float* h_pf = out;                         // 20000*128
    float* o_gw = out + (size_t)N_PFAS * 128;  // 100000
    float* o_sw = o_gw + N_GW;                 // 30000

    // ---- workspace layout ----
    char* p = (char*)d_ws;
    auto alloc = [&](size_t bytes) { char* q = p; p += (bytes + 15) & ~(size_t)15; return q; };
    unsigned short* bufT_pg = (unsigned short*)alloc((size_t)N_PFAS * 128 * 2);
    unsigned short* bufT_ps = (unsigned short*)alloc((size_t)N_PFAS * 128 * 2);
    float* mean_gp = (float*)alloc((size_t)N_PFAS * 128 * 4);
    float* mean_sp = (float*)alloc((size_t)N_PFAS * 128 * 4);
    int* perm_all   = (int*)alloc((size_t)E_TOT * 4);
    int* off_all    = (int*)alloc((size_t)(NTOT + 1) * 4);
    int* counts     = (int*)alloc((size_t)NTOT * 4);
    int* cursor_all = (int*)alloc((size_t)NTOT * 4);
    int* blockSums  = (int*)alloc((size_t)SCAN_NBLK * 4);

    // ---- 1. transforms of the pfas source side (bf16 out) ----
    dim3 gT((N_PFAS + 127) / 128, 2);
    gemm_t16_kernel<<<gT, 256, 0, stream>>>(
        N_PFAS, x_pfas, Wl_pg, bufT_pg, Wl_ps, bufT_ps);

    // ---- 2. fused CSR build (concat counts -> 3-phase scan -> permute) ----
    hipMemsetAsync(counts, 0, (size_t)NTOT * 4, stream);
    hist_all_kernel<<<(E_TOT + 255) / 256, 256, 0, stream>>>(
        ei_pg_dst, ei_ps_dst, ei_gp_dst, ei_sp_dst, counts);
    scanA_kernel<<<SCAN_NBLK, 256, 0, stream>>>(counts, blockSums);
    scanB_kernel<<<1, 128, 0, stream>>>(blockSums, off_all);
    scanC_kernel<<<SCAN_NBLK, 256, 0, stream>>>(counts, blockSums, off_all, cursor_all);
    permute_all_kernel<<<(E_TOT + 255) / 256, 256, 0, stream>>>(
        ei_pg_src, ei_pg_dst, ei_ps_src, ei_ps_dst,
        ei_gp_src, ei_gp_dst, ei_sp_src, ei_sp_dst,
        cursor_all, perm_all);

    // ---- 3. gw / sw fused node passes ----
    gemm_gather_scalar_kernel<<<(N_GW + 127) / 128, 512, 0, stream>>>(
        N_GW, x_gw, Wr_pg, bl_pg, bufT_pg, perm_all, off_all + BASE_PG,
        W_gw, b_gw, o_gw);
    gemm_gather_scalar_kernel<<<(N_SW + 127) / 128, 512, 0, stream>>>(
        N_SW, x_sw, Wr_ps, bl_ps, bufT_ps, perm_all, off_all + BASE_PS,
        W_sw, b_sw, o_sw);

    // ---- 4. raw segmented means into pfas ----
    dim3 gM((N_PFAS + 3) / 4, 2);
    seg_mean_kernel<<<gM, 256, 0, stream>>>(
        (const float2*)x_gw, off_all + BASE_GP, (float2*)mean_gp,
        (const float2*)x_sw, off_all + BASE_SP, (float2*)mean_sp,
        perm_all, N_PFAS);

    // ---- 5. pfas fused node pass ----
    gemm_pf3_kernel<<<(N_PFAS + 127) / 128, 256, 0, stream>>>(
        N_PFAS, x_pfas, Wr_gp, Wr_sp, mean_gp, Wl_gp, mean_sp, Wl_sp,
        bl_gp, bl_sp, h_pf);
}

// Round 6
// 726.978 us; speedup vs baseline: 7.8486x; 1.2828x over previous
//
#include <hip/hip_runtime.h>

// ---------------------------------------------------------------------------
// Problem constants
// ---------------------------------------------------------------------------
#define N_PFAS 20000
#define N_GW   100000
#define N_SW   30000
#define E_PG   1600000
#define E_GP   640000
#define E_PS   480000
#define E_SP   320000
#define E_TOT  (E_PG + E_PS + E_GP + E_SP)
// Concatenated node-count layout: [pg: N_GW][ps: N_SW][gp: N_PFAS][sp: N_PFAS]
#define BASE_PG 0
#define BASE_PS (N_GW)
#define BASE_GP (N_GW + N_SW)
#define BASE_SP (N_GW + N_SW + N_PFAS)
#define NTOT    (N_GW + N_SW + 2 * N_PFAS)
#define SCAN_NBLK ((NTOT + 2047) / 2048)
// Bucketed permute: 256 nodes per bucket.
#define NB        ((NTOT + 255) / 256)       // 665
#define BIN_EPT   12                         // edges per thread in bin pass
#define BIN_EPB   (1024 * BIN_EPT)           // 12288 edges per block
#define BIN_NBLK  ((E_TOT + BIN_EPB - 1) / BIN_EPB)
#define SEG_CAP   15360                      // LDS perm-segment capacity

// ---------------------------------------------------------------------------
// bf16 helpers (RNE pack, cheap unpack)
// ---------------------------------------------------------------------------
__device__ __forceinline__ unsigned short f2bf(float f) {
    unsigned u = __float_as_uint(f);
    u += 0x7fffu + ((u >> 16) & 1u);
    return (unsigned short)(u >> 16);
}
__device__ __forceinline__ float u2f(unsigned u) { return __uint_as_float(u); }

// ---------------------------------------------------------------------------
// Shared 128x128 GEMM tile: NT threads, 128 rows/block, 32-k chunks in LDS.
// ---------------------------------------------------------------------------
template<int NT>
__device__ __forceinline__ void tile_gemm(
    const float* __restrict__ X, const float* __restrict__ Wa,
    const float* __restrict__ Wb, int n, int row0, int tid,
    float4* sW4, float* sX, float4* acc)
{
    constexpr int TY  = NT / 32;
    constexpr int RPT = 128 / TY;
    const int tx = tid & 31;
    const int ty = tid >> 5;
    const float4* X4 = (const float4*)X;
    const float4* Wa4 = (const float4*)Wa;
    const float4* Wb4 = (const float4*)Wb;

    for (int kc = 0; kc < 4; ++kc) {
        __syncthreads();
        for (int i = tid; i < 1024; i += NT) {
            float4 w = Wa4[kc * 1024 + i];
            if (Wb) {
                float4 b = Wb4[kc * 1024 + i];
                w.x += b.x; w.y += b.y; w.z += b.z; w.w += b.w;
            }
            sW4[i] = w;
        }
        for (int j = tid; j < 1024; j += NT) {
            int rr = j >> 3, k4 = j & 7;
            int r = row0 + rr;
            float4 xv = make_float4(0.f, 0.f, 0.f, 0.f);
            if (r < n) xv = X4[(size_t)r * 32 + kc * 8 + k4];
            int kk = k4 * 4;
            sX[(kk + 0) * 128 + rr] = xv.x;
            sX[(kk + 1) * 128 + rr] = xv.y;
            sX[(kk + 2) * 128 + rr] = xv.z;
            sX[(kk + 3) * 128 + rr] = xv.w;
        }
        __syncthreads();
#pragma unroll 4
        for (int k = 0; k < 32; ++k) {
            float4 w4 = sW4[k * 32 + tx];
            const float4* xr4 = (const float4*)&sX[k * 128 + ty * RPT];
#pragma unroll
            for (int q = 0; q < RPT / 4; ++q) {
                float4 x4 = xr4[q];
                acc[q * 4 + 0].x += x4.x * w4.x; acc[q * 4 + 0].y += x4.x * w4.y;
                acc[q * 4 + 0].z += x4.x * w4.z; acc[q * 4 + 0].w += x4.x * w4.w;
                acc[q * 4 + 1].x += x4.y * w4.x; acc[q * 4 + 1].y += x4.y * w4.y;
                acc[q * 4 + 1].z += x4.y * w4.z; acc[q * 4 + 1].w += x4.y * w4.w;
                acc[q * 4 + 2].x += x4.z * w4.x; acc[q * 4 + 2].y += x4.z * w4.y;
                acc[q * 4 + 2].z += x4.z * w4.z; acc[q * 4 + 2].w += x4.z * w4.w;
                acc[q * 4 + 3].x += x4.w * w4.x; acc[q * 4 + 3].y += x4.w * w4.y;
                acc[q * 4 + 3].z += x4.w * w4.z; acc[q * 4 + 3].w += x4.w * w4.w;
            }
        }
    }
}

// ---------------------------------------------------------------------------
// bufT16 = X @ W  (bf16 output). grid.y selects (W0,out0) vs (W1,out1).
// ---------------------------------------------------------------------------
__global__ __launch_bounds__(256) void gemm_t16_kernel(
    int n, const float* __restrict__ X,
    const float* __restrict__ W0, unsigned short* __restrict__ out0,
    const float* __restrict__ W1, unsigned short* __restrict__ out1)
{
    __shared__ float sW[32 * 128];
    __shared__ float sX[32 * 128];
    const int tid = threadIdx.x;
    const int row0 = blockIdx.x * 128;
    const float* W = (blockIdx.y == 0) ? W0 : W1;
    unsigned short* out = (blockIdx.y == 0) ? out0 : out1;

    float4 acc[16];
#pragma unroll
    for (int i = 0; i < 16; ++i) acc[i] = make_float4(0.f, 0.f, 0.f, 0.f);
    tile_gemm<256>(X, W, nullptr, n, row0, tid, (float4*)sW, sX, acc);

    const int tx = tid & 31;
    const int rbase = row0 + (tid >> 5) * 16;
#pragma unroll
    for (int rr = 0; rr < 16; ++rr) {
        int r = rbase + rr;
        if (r < n) {
            uint2 o;
            o.x = (unsigned)f2bf(acc[rr].x) | ((unsigned)f2bf(acc[rr].y) << 16);
            o.y = (unsigned)f2bf(acc[rr].z) | ((unsigned)f2bf(acc[rr].w) << 16);
            *(uint2*)(out + (size_t)r * 128 + tx * 4) = o;
        }
    }
}

// ---------------------------------------------------------------------------
// gw/sw node pass, 512 threads: GEMM X@Wr fused with CSR gather of bf16
// transformed neighbor rows + scalar head.
// ---------------------------------------------------------------------------
__global__ __launch_bounds__(512, 8) void gemm_gather_scalar_kernel(
    int n, const float* __restrict__ X, const float* __restrict__ Wr,
    const float* __restrict__ bl,
    const unsigned short* __restrict__ bufT16, const int* __restrict__ perm,
    const int* __restrict__ off,
    const float* __restrict__ wout, const float* __restrict__ bout,
    float* __restrict__ out)
{
    __shared__ float sW[32 * 128];
    __shared__ float sX[32 * 128];
    const int tid = threadIdx.x;
    const int row0 = blockIdx.x * 128;
    float4 acc[8];
#pragma unroll
    for (int i = 0; i < 8; ++i) acc[i] = make_float4(0.f, 0.f, 0.f, 0.f);
    tile_gemm<512>(X, Wr, nullptr, n, row0, tid, (float4*)sW, sX, acc);

    const int tx = tid & 31;
    const int rbase = row0 + (tid >> 5) * 8;
    float4 bv = ((const float4*)bl)[tx];
    float4 wo = ((const float4*)wout)[tx];
    float bo = bout[0];

#pragma unroll 1
    for (int rr = 0; rr < 8; ++rr) {
        int r = rbase + rr;
        int lo = 0, hi = 0;
        if (r < n) { lo = off[r]; hi = off[r + 1]; }
        float4 s0 = make_float4(0.f, 0.f, 0.f, 0.f);
        float4 s1 = make_float4(0.f, 0.f, 0.f, 0.f);
        int i = lo;
        for (; i + 2 <= hi; i += 2) {
            int a = perm[i];
            int b = perm[i + 1];
            uint2 va = *(const uint2*)(bufT16 + (size_t)a * 128 + tx * 4);
            uint2 vb = *(const uint2*)(bufT16 + (size_t)b * 128 + tx * 4);
            s0.x += u2f(va.x << 16); s0.y += u2f(va.x & 0xffff0000u);
            s0.z += u2f(va.y << 16); s0.w += u2f(va.y & 0xffff0000u);
            s1.x += u2f(vb.x << 16); s1.y += u2f(vb.x & 0xffff0000u);
            s1.z += u2f(vb.y << 16); s1.w += u2f(vb.y & 0xffff0000u);
        }
        if (i < hi) {
            int a = perm[i];
            uint2 va = *(const uint2*)(bufT16 + (size_t)a * 128 + tx * 4);
            s0.x += u2f(va.x << 16); s0.y += u2f(va.x & 0xffff0000u);
            s0.z += u2f(va.y << 16); s0.w += u2f(va.y & 0xffff0000u);
        }
        float inv = 1.0f / fmaxf((float)(hi - lo), 1.0f);
        float h0 = fmaxf(acc[rr].x + bv.x + (s0.x + s1.x) * inv, 0.f);
        float h1 = fmaxf(acc[rr].y + bv.y + (s0.y + s1.y) * inv, 0.f);
        float h2 = fmaxf(acc[rr].z + bv.z + (s0.z + s1.z) * inv, 0.f);
        float h3 = fmaxf(acc[rr].w + bv.w + (s0.w + s1.w) * inv, 0.f);
        float p = h0 * wo.x + h1 * wo.y + h2 * wo.z + h3 * wo.w;
        p += __shfl_xor(p, 1, 32);
        p += __shfl_xor(p, 2, 32);
        p += __shfl_xor(p, 4, 32);
        p += __shfl_xor(p, 8, 32);
        p += __shfl_xor(p, 16, 32);
        if (tx == 0 && r < n) out[r] = p + bo;
    }
}

// ---------------------------------------------------------------------------
// pfas node pass: h_pf = relu(mean_g@Wl_g + mean_s@Wl_s + x@(WrA+WrB) + blG+blS)
// ---------------------------------------------------------------------------
__global__ __launch_bounds__(256) void gemm_pf3_kernel(
    int n, const float* __restrict__ x,
    const float* __restrict__ WrA, const float* __restrict__ WrB,
    const float* __restrict__ mean_g, const float* __restrict__ Wl_g,
    const float* __restrict__ mean_s, const float* __restrict__ Wl_s,
    const float* __restrict__ blG, const float* __restrict__ blS,
    float* __restrict__ out)
{
    __shared__ float sW[32 * 128];
    __shared__ float sX[32 * 128];
    const int tid = threadIdx.x;
    const int row0 = blockIdx.x * 128;
    float4 acc[16];
#pragma unroll
    for (int i = 0; i < 16; ++i) acc[i] = make_float4(0.f, 0.f, 0.f, 0.f);
    tile_gemm<256>(mean_g, Wl_g, nullptr, n, row0, tid, (float4*)sW, sX, acc);
    tile_gemm<256>(mean_s, Wl_s, nullptr, n, row0, tid, (float4*)sW, sX, acc);
    tile_gemm<256>(x, WrA, WrB, n, row0, tid, (float4*)sW, sX, acc);

    const int tx = tid & 31;
    const int rbase = row0 + (tid >> 5) * 16;
    float4 b1 = ((const float4*)blG)[tx];
    float4 b2 = ((const float4*)blS)[tx];
#pragma unroll
    for (int rr = 0; rr < 16; ++rr) {
        int r = rbase + rr;
        if (r < n) {
            float4 o = acc[rr];
            o.x = fmaxf(o.x + b1.x + b2.x, 0.f);
            o.y = fmaxf(o.y + b1.y + b2.y, 0.f);
            o.z = fmaxf(o.z + b1.z + b2.z, 0.f);
            o.w = fmaxf(o.w + b1.w + b2.w, 0.f);
            ((float4*)out)[(size_t)r * 32 + tx] = o;
        }
    }
}

// ---------------------------------------------------------------------------
// Histogram into concatenated counts array.
// ---------------------------------------------------------------------------
__global__ __launch_bounds__(256) void hist_all_kernel(
    const int* __restrict__ d_pg, const int* __restrict__ d_ps,
    const int* __restrict__ d_gp, const int* __restrict__ d_sp,
    int* __restrict__ counts)
{
    int e = blockIdx.x * 256 + threadIdx.x;
    if (e < E_PG) atomicAdd(&counts[BASE_PG + d_pg[e]], 1);
    else if (e < E_PG + E_PS) atomicAdd(&counts[BASE_PS + d_ps[e - E_PG]], 1);
    else if (e < E_PG + E_PS + E_GP) atomicAdd(&counts[BASE_GP + d_gp[e - E_PG - E_PS]], 1);
    else if (e < E_TOT) atomicAdd(&counts[BASE_SP + d_sp[e - E_PG - E_PS - E_GP]], 1);
}

// ---------------------------------------------------------------------------
// 3-phase global exclusive scan over NTOT concatenated counts.
// ---------------------------------------------------------------------------
__global__ __launch_bounds__(256) void scanA_kernel(
    const int* __restrict__ counts, int* __restrict__ blockSums)
{
    __shared__ int red[256];
    int base = blockIdx.x * 2048;
    int s = 0;
#pragma unroll
    for (int i = 0; i < 8; ++i) {
        int idx = base + i * 256 + threadIdx.x;
        if (idx < NTOT) s += counts[idx];
    }
    red[threadIdx.x] = s;
    __syncthreads();
    for (int ofs = 128; ofs > 0; ofs >>= 1) {
        if (threadIdx.x < ofs) red[threadIdx.x] += red[threadIdx.x + ofs];
        __syncthreads();
    }
    if (threadIdx.x == 0) blockSums[blockIdx.x] = red[0];
}

__global__ __launch_bounds__(128) void scanB_kernel(
    int* __restrict__ blockSums, int* __restrict__ off_all)
{
    __shared__ int sp[128];
    int t = threadIdx.x;
    int v = (t < SCAN_NBLK) ? blockSums[t] : 0;
    sp[t] = v;
    __syncthreads();
    for (int ofs = 1; ofs < 128; ofs <<= 1) {
        int add = (t >= ofs) ? sp[t - ofs] : 0;
        __syncthreads();
        sp[t] += add;
        __syncthreads();
    }
    if (t < SCAN_NBLK) blockSums[t] = sp[t] - v;   // exclusive prefix
    if (t == 0) off_all[NTOT] = E_TOT;
}

// Phase C: write off_all; also seed per-bucket global cursors (gcursor).
__global__ __launch_bounds__(256) void scanC_kernel(
    const int* __restrict__ counts, const int* __restrict__ blockSums,
    int* __restrict__ off_all, int* __restrict__ gcursor)
{
    __shared__ int sp[256];
    const int t = threadIdx.x;
    const int myBase = blockIdx.x * 2048 + t * 8;
    int c[8];
    int s = 0;
#pragma unroll
    for (int i = 0; i < 8; ++i) {
        int idx = myBase + i;
        c[i] = (idx < NTOT) ? counts[idx] : 0;
        s += c[i];
    }
    sp[t] = s;
    __syncthreads();
    for (int ofs = 1; ofs < 256; ofs <<= 1) {
        int add = (t >= ofs) ? sp[t - ofs] : 0;
        __syncthreads();
        sp[t] += add;
        __syncthreads();
    }
    int run = blockSums[blockIdx.x] + sp[t] - s;
#pragma unroll
    for (int i = 0; i < 8; ++i) {
        int idx = myBase + i;
        if (idx < NTOT) {
            off_all[idx] = run;
            if ((idx & 255) == 0) gcursor[idx >> 8] = run;
        }
        run += c[i];
    }
}

// ---------------------------------------------------------------------------
// Pass 1: bin edges into 256-node buckets. Entry packed: (idx&255) | (src<<8).
// ---------------------------------------------------------------------------
__global__ __launch_bounds__(1024) void bin_kernel(
    const int* __restrict__ s_pg, const int* __restrict__ d_pg,
    const int* __restrict__ s_ps, const int* __restrict__ d_ps,
    const int* __restrict__ s_gp, const int* __restrict__ d_gp,
    const int* __restrict__ s_sp, const int* __restrict__ d_sp,
    int* __restrict__ gcursor, unsigned* __restrict__ pairs)
{
    __shared__ int hist[NB];
    __shared__ int chunkBase[NB];
    const int tid = threadIdx.x;
    for (int i = tid; i < NB; i += 1024) hist[i] = 0;
    __syncthreads();

    const int base = blockIdx.x * BIN_EPB;
    int bkt[BIN_EPT], rnk[BIN_EPT];
    unsigned pk[BIN_EPT];
#pragma unroll
    for (int k = 0; k < BIN_EPT; ++k) {
        int e = base + k * 1024 + tid;
        int idx = -1, src = 0;
        if (e < E_PG) { idx = BASE_PG + d_pg[e]; src = s_pg[e]; }
        else if (e < E_PG + E_PS) { int i2 = e - E_PG; idx = BASE_PS + d_ps[i2]; src = s_ps[i2]; }
        else if (e < E_PG + E_PS + E_GP) { int i2 = e - E_PG - E_PS; idx = BASE_GP + d_gp[i2]; src = s_gp[i2]; }
        else if (e < E_TOT) { int i2 = e - E_PG - E_PS - E_GP; idx = BASE_SP + d_sp[i2]; src = s_sp[i2]; }
        if (idx >= 0) {
            int b = idx >> 8;
            bkt[k] = b;
            rnk[k] = atomicAdd(&hist[b], 1);
            pk[k] = (unsigned)(idx & 255) | ((unsigned)src << 8);
        } else bkt[k] = -1;
    }
    __syncthreads();
    for (int i = tid; i < NB; i += 1024) {
        int c = hist[i];
        chunkBase[i] = c ? atomicAdd(&gcursor[i], c) : 0;
    }
    __syncthreads();
#pragma unroll
    for (int k = 0; k < BIN_EPT; ++k)
        if (bkt[k] >= 0) pairs[chunkBase[bkt[k]] + rnk[k]] = pk[k];
}

// ---------------------------------------------------------------------------
// Pass 2: one block per bucket; scatter into LDS segment, stream out coalesced.
// ---------------------------------------------------------------------------
__global__ __launch_bounds__(1024) void unbin_kernel(
    const unsigned* __restrict__ pairs, const int* __restrict__ off_all,
    int* __restrict__ perm_all)
{
    __shared__ int sPerm[SEG_CAP];
    __shared__ int cur[256];
    const int b = blockIdx.x;
    const int nb0 = b << 8;
    const int nb1 = min(nb0 + 256, NTOT);
    const int tid = threadIdx.x;
    const int base = off_all[nb0];
    const int end  = off_all[nb1];
    const int len = end - base;
    if (tid < nb1 - nb0) cur[tid] = off_all[nb0 + tid] - base;
    __syncthreads();

    if (len <= SEG_CAP) {
        for (int i = base + tid; i < end; i += 1024) {
            unsigned p = pairs[i];
            int pos = atomicAdd(&cur[p & 255u], 1);
            sPerm[pos] = (int)(p >> 8);
        }
        __syncthreads();
        for (int i = tid; i < len; i += 1024)
            perm_all[base + i] = sPerm[i];
    } else {
        for (int i = base + tid; i < end; i += 1024) {
            unsigned p = pairs[i];
            int pos = atomicAdd(&cur[p & 255u], 1);
            perm_all[base + pos] = (int)(p >> 8);
        }
    }
}

// ---------------------------------------------------------------------------
// Segmented mean of raw fp32 source features: one 64-lane wave per dst node.
// ---------------------------------------------------------------------------
__global__ __launch_bounds__(256) void seg_mean_kernel(
    const float2* __restrict__ x0, const int* __restrict__ off0,
    float2* __restrict__ mean0,
    const float2* __restrict__ x1, const int* __restrict__ off1,
    float2* __restrict__ mean1,
    const int* __restrict__ perm_all, int n)
{
    const float2* xsrc; const int* off; float2* mean;
    if (blockIdx.y == 0) { xsrc = x0; off = off0; mean = mean0; }
    else                 { xsrc = x1; off = off1; mean = mean1; }

    int node = blockIdx.x * 4 + (threadIdx.x >> 6);
    if (node >= n) return;
    int lane = threadIdx.x & 63;
    int lo = off[node], hi = off[node + 1];
    float2 a0 = make_float2(0.f, 0.f);
    float2 a1 = make_float2(0.f, 0.f);
    int i = lo;
    for (; i + 2 <= hi; i += 2) {
        int sa = perm_all[i];
        int sb = perm_all[i + 1];
        float2 va = xsrc[(size_t)sa * 64 + lane];
        float2 vb = xsrc[(size_t)sb * 64 + lane];
        a0.x += va.x; a0.y += va.y;
        a1.x += vb.x; a1.y += vb.y;
    }
    if (i < hi) {
        int sa = perm_all[i];
        float2 va = xsrc[(size_t)sa * 64 + lane];
        a0.x += va.x; a0.y += va.y;
    }
    float inv = 1.0f / fmaxf((float)(hi - lo), 1.0f);
    mean[(size_t)node * 64 + lane] = make_float2((a0.x + a1.x) * inv, (a0.y + a1.y) * inv);
}

// ---------------------------------------------------------------------------
// Launch
// ---------------------------------------------------------------------------
extern "C" void kernel_launch(void* const* d_in, const int* in_sizes, int n_in,
                              void* d_out, int out_size, void* d_ws, size_t ws_size,
                              hipStream_t stream)
{
    const float* x_pfas = (const float*)d_in[0];
    const float* x_gw   = (const float*)d_in[1];
    const float* x_sw   = (const float*)d_in[2];
    const int* ei_pg_src = (const int*)d_in[3];
    const int* ei_pg_dst = (const int*)d_in[4];
    const int* ei_gp_src = (const int*)d_in[5];
    const int* ei_gp_dst = (const int*)d_in[6];
    const int* ei_ps_src = (const int*)d_in[7];
    const int* ei_ps_dst = (const int*)d_in[8];
    const int* ei_sp_src = (const int*)d_in[9];
    const int* ei_sp_dst = (const int*)d_in[10];
    const float* Wl_pg = (const float*)d_in[11];
    const float* bl_pg = (const float*)d_in[12];
    const float* Wr_pg = (const float*)d_in[13];
    const float* Wl_gp = (const float*)d_in[14];
    const float* bl_gp = (const float*)d_in[15];
    const float* Wr_gp = (const float*)d_in[16];
    const float* Wl_ps = (const float*)d_in[17];
    const float* bl_ps = (const float*)d_in[18];
    const float* Wr_ps = (const float*)d_in[19];
    const float* Wl_sp = (const float*)d_in[20];
    const float* bl_sp = (const float*)d_in[21];
    const float* Wr_sp = (const float*)d_in[22];
    const float* W_gw = (const float*)d_in[23];
    const float* b_gw = (const float*)d_in[24];
    const float* W_sw = (const float*)d_in[25];
    const float* b_sw = (const float*)d_in[26];

    float* out  = (float*)d_out;
    float* h_pf = out;                         // 20000*128
    float* o_gw = out + (size_t)N_PFAS * 128;  // 100000
    float* o_sw = o_gw + N_GW;                 // 30000

    // ---- workspace layout (~56 MB) ----
    char* p = (char*)d_ws;
    auto alloc = [&](size_t bytes) { char* q = p; p += (bytes + 15) & ~(size_t)15; return q; };
    unsigned short* bufT_pg = (unsigned short*)alloc((size_t)N_PFAS * 128 * 2);
    unsigned short* bufT_ps = (unsigned short*)alloc((size_t)N_PFAS * 128 * 2);
    float* mean_gp = (float*)alloc((size_t)N_PFAS * 128 * 4);
    float* mean_sp = (float*)alloc((size_t)N_PFAS * 128 * 4);
    int* perm_all   = (int*)alloc((size_t)E_TOT * 4);
    unsigned* pairs = (unsigned*)alloc((size_t)E_TOT * 4);
    int* off_all    = (int*)alloc((size_t)(NTOT + 1) * 4);
    int* counts     = (int*)alloc((size_t)NTOT * 4);
    int* gcursor    = (int*)alloc((size_t)NB * 4);
    int* blockSums  = (int*)alloc((size_t)SCAN_NBLK * 4);

    // ---- 1. transforms of the pfas source side (bf16 out) ----
    dim3 gT((N_PFAS + 127) / 128, 2);
    gemm_t16_kernel<<<gT, 256, 0, stream>>>(
        N_PFAS, x_pfas, Wl_pg, bufT_pg, Wl_ps, bufT_ps);

    // ---- 2. CSR build: hist -> scan -> bucketed permute ----
    hipMemsetAsync(counts, 0, (size_t)NTOT * 4, stream);
    hist_all_kernel<<<(E_TOT + 255) / 256, 256, 0, stream>>>(
        ei_pg_dst, ei_ps_dst, ei_gp_dst, ei_sp_dst, counts);
    scanA_kernel<<<SCAN_NBLK, 256, 0, stream>>>(counts, blockSums);
    scanB_kernel<<<1, 128, 0, stream>>>(blockSums, off_all);
    scanC_kernel<<<SCAN_NBLK, 256, 0, stream>>>(counts, blockSums, off_all, gcursor);
    bin_kernel<<<BIN_NBLK, 1024, 0, stream>>>(
        ei_pg_src, ei_pg_dst, ei_ps_src, ei_ps_dst,
        ei_gp_src, ei_gp_dst, ei_sp_src, ei_sp_dst, gcursor, pairs);
    unbin_kernel<<<NB, 1024, 0, stream>>>(pairs, off_all, perm_all);

    // ---- 3. gw / sw fused node passes ----
    gemm_gather_scalar_kernel<<<(N_GW + 127) / 128, 512, 0, stream>>>(
        N_GW, x_gw, Wr_pg, bl_pg, bufT_pg, perm_all, off_all + BASE_PG,
        W_gw, b_gw, o_gw);
    gemm_gather_scalar_kernel<<<(N_SW + 127) / 128, 512, 0, stream>>>(
        N_SW, x_sw, Wr_ps, bl_ps, bufT_ps, perm_all, off_all + BASE_PS,
        W_sw, b_sw, o_sw);

    // ---- 4. raw segmented means into pfas ----
    dim3 gM((N_PFAS + 3) / 4, 2);
    seg_mean_kernel<<<gM, 256, 0, stream>>>(
        (const float2*)x_gw, off_all + BASE_GP, (float2*)mean_gp,
        (const float2*)x_sw, off_all + BASE_SP, (float2*)mean_sp,
        perm_all, N_PFAS);

    // ---- 5. pfas fused node pass ----
    gemm_pf3_kernel<<<(N_PFAS + 127) / 128, 256, 0, stream>>>(
        N_PFAS, x_pfas, Wr_gp, Wr_sp, mean_gp, Wl_gp, mean_sp, Wl_sp,
        bl_gp, bl_sp, h_pf);
}